// Round 1
// baseline (229.734 us; speedup 1.0000x reference)
//
#include <hip/hip_runtime.h>
#include <math.h>

// Problem constants (AttentionLikeModel_75531294867774)
#define DIMM    1024
#define NHEADS  16
#define HDIM    64
#define BATCH   2
#define SEQ     2048
#define ROWS    (BATCH*SEQ)   // 4096

typedef _Float16 f16x8 __attribute__((ext_vector_type(8)));
typedef _Float16 f16x4 __attribute__((ext_vector_type(4)));
typedef float    f32x4 __attribute__((ext_vector_type(4)));

__device__ inline void gl_lds16(const void* g, void* l) {
    __builtin_amdgcn_global_load_lds(
        (const __attribute__((address_space(1))) void*)g,
        (__attribute__((address_space(3))) void*)l, 16, 0, 0);
}

// ---------------------------------------------------------------------------
// Merged prep: blocks [0,2048) cvt x -> fp16; [2048,2816) W_qkv^T; [2816,3072) W_out^T
// ---------------------------------------------------------------------------
__device__ void tcvt64(const float* __restrict__ in, _Float16* __restrict__ out,
                       int K, int N, int k0, int n0, float (*tile)[65], int t)
{
    {
        const int c4 = (t & 15) * 4;
        const int r  = t >> 4;
        #pragma unroll
        for (int i = 0; i < 4; i++) {
            const int rr = r + 16 * i;
            float4 v = *(const float4*)(in + (size_t)(k0 + rr) * N + n0 + c4);
            tile[rr][c4] = v.x; tile[rr][c4 + 1] = v.y;
            tile[rr][c4 + 2] = v.z; tile[rr][c4 + 3] = v.w;
        }
    }
    __syncthreads();
    #pragma unroll
    for (int i = 0; i < 2; i++) {
        const int seg = t + 256 * i;
        const int n   = seg >> 3;
        const int kc  = (seg & 7) * 8;
        f16x8 o;
        #pragma unroll
        for (int j = 0; j < 8; j++) o[j] = (_Float16)tile[kc + j][n];
        *(f16x8*)(out + (size_t)(n0 + n) * K + k0 + kc) = o;
    }
}

__global__ __launch_bounds__(256)
void prep_kernel(const float* __restrict__ x, const float* __restrict__ Wqkv,
                 const float* __restrict__ Wout, _Float16* __restrict__ xh,
                 _Float16* __restrict__ wqkvt, _Float16* __restrict__ woutt)
{
    __shared__ float tile[64][65];
    const int bx = blockIdx.x;
    const int t  = threadIdx.x;
    if (bx < 2048) {                       // cvt x (4096x1024 / 8 / 256 = 2048 blocks)
        const int i = bx * 256 + t;
        const float4 a = *(const float4*)(x + (size_t)i * 8);
        const float4 b = *(const float4*)(x + (size_t)i * 8 + 4);
        f16x8 o;
        o[0] = (_Float16)a.x; o[1] = (_Float16)a.y; o[2] = (_Float16)a.z; o[3] = (_Float16)a.w;
        o[4] = (_Float16)b.x; o[5] = (_Float16)b.y; o[6] = (_Float16)b.z; o[7] = (_Float16)b.w;
        *(f16x8*)(xh + (size_t)i * 8) = o;
    } else if (bx < 2816) {                // W_qkv^T: grid (48,16)
        const int id = bx - 2048;
        const int gx = id % 48, gy = id / 48;
        tcvt64(Wqkv, wqkvt, DIMM, 3 * DIMM, gy * 64, gx * 64, tile, t);
    } else {                               // W_out^T: grid (16,16)
        const int id = bx - 2816;
        const int gx = id & 15, gy = id >> 4;
        tcvt64(Wout, woutt, DIMM, DIMM, gy * 64, gx * 64, tile, t);
    }
}

// ---------------------------------------------------------------------------
// V-transpose: qkvh V-third [b][key][h*64+d] -> vt[bh][d][key] (fp16)
// ---------------------------------------------------------------------------
__global__ __launch_bounds__(256)
void vtranspose_kernel(const _Float16* __restrict__ qkvh, _Float16* __restrict__ vt)
{
    __shared__ _Float16 tile[64][72];
    const int kt = blockIdx.x;
    const int bh = blockIdx.y;
    const int b  = bh >> 4, h = bh & 15;
    const int t  = threadIdx.x;
    {
        const int key = t >> 2, c4 = (t & 3) * 16;
        const _Float16* src = qkvh + ((size_t)(b * SEQ + kt * 64 + key)) * (3 * DIMM)
                              + 2 * DIMM + h * HDIM + c4;
        f16x8 v0 = *(const f16x8*)src;
        f16x8 v1 = *(const f16x8*)(src + 8);
        #pragma unroll
        for (int j = 0; j < 8; j++) {
            tile[c4 + j][key]     = v0[j];
            tile[c4 + 8 + j][key] = v1[j];
        }
    }
    __syncthreads();
    {
        const int d = t >> 2, k4 = (t & 3) * 16;
        f16x8 o0, o1;
        #pragma unroll
        for (int j = 0; j < 8; j++) { o0[j] = tile[d][k4 + j]; o1[j] = tile[d][k4 + 8 + j]; }
        _Float16* dst = vt + ((size_t)bh * 64 + d) * SEQ + kt * 64 + k4;
        *(f16x8*)dst       = o0;
        *(f16x8*)(dst + 8) = o1;
    }
}

// ---------------------------------------------------------------------------
// HGEMM + bias, BK=64 (m97 config): 128x128x64 tile, 32 MFMA per barrier pair.
// ---------------------------------------------------------------------------
template<int OUT_F16>
__global__ __launch_bounds__(256)
void hgemm_bias_kernel(const _Float16* __restrict__ A, const _Float16* __restrict__ Bt,
                       const float* __restrict__ bias, void* __restrict__ Cout,
                       int N, int K)
{
    __shared__ _Float16 As[128 * 64];
    __shared__ _Float16 Bs[128 * 64];

    const int t    = threadIdx.x;
    const int w    = t >> 6, lane = t & 63;
    const int quad = lane >> 4, l16 = lane & 15;
    const int wr   = w >> 1, wc = w & 1;
    const int row0 = blockIdx.y * 128, col0 = blockIdx.x * 128;
    const int sw   = l16 & 7;

    f32x4 acc[4][4];
    #pragma unroll
    for (int i = 0; i < 4; i++)
        #pragma unroll
        for (int j = 0; j < 4; j++)
            #pragma unroll
            for (int r = 0; r < 4; r++) acc[i][j][r] = 0.f;

    const _Float16* gA[4];
    const _Float16* gB[4];
    int lofs[4];
    #pragma unroll
    for (int j = 0; j < 4; j++) {
        const int s   = t + 256 * j;
        const int row = s >> 3;
        const int kb  = (s & 7) ^ (row & 7);
        gA[j] = A  + (size_t)(row0 + row) * K + kb * 8;
        gB[j] = Bt + (size_t)(col0 + row) * K + kb * 8;
        lofs[j] = s * 8;
    }

    const int niter = K >> 6;
    #pragma unroll 1
    for (int it = 0; it < niter; it++) {
        __syncthreads();
        #pragma unroll
        for (int j = 0; j < 4; j++) gl_lds16(gA[j], As + lofs[j]);
        #pragma unroll
        for (int j = 0; j < 4; j++) gl_lds16(gB[j], Bs + lofs[j]);
        #pragma unroll
        for (int j = 0; j < 4; j++) { gA[j] += 64; gB[j] += 64; }
        __syncthreads();

        f16x8 af[4][2], bf[4][2];
        #pragma unroll
        for (int i = 0; i < 4; i++) {
            const int arow = wr * 64 + i * 16 + l16;
            const int brow = wc * 64 + i * 16 + l16;
            #pragma unroll
            for (int hh = 0; hh < 2; hh++) {
                af[i][hh] = *(const f16x8*)(As + (arow * 8 + ((hh * 4 + quad) ^ sw)) * 8);
                bf[i][hh] = *(const f16x8*)(Bs + (brow * 8 + ((hh * 4 + quad) ^ sw)) * 8);
            }
        }
        #pragma unroll
        for (int i = 0; i < 4; i++)
            #pragma unroll
            for (int j = 0; j < 4; j++) {
                acc[i][j] = __builtin_amdgcn_mfma_f32_16x16x32_f16(af[i][0], bf[j][0], acc[i][j], 0, 0, 0);
                acc[i][j] = __builtin_amdgcn_mfma_f32_16x16x32_f16(af[i][1], bf[j][1], acc[i][j], 0, 0, 0);
            }
    }

    #pragma unroll
    for (int j = 0; j < 4; j++) {
        const int col = col0 + wc * 64 + j * 16 + l16;
        const float bv = bias[col];
        #pragma unroll
        for (int i = 0; i < 4; i++) {
            const int row = row0 + wr * 64 + i * 16 + quad * 4;
            #pragma unroll
            for (int r = 0; r < 4; r++) {
                const float v = acc[i][j][r] + bv;
                if (OUT_F16)
                    ((_Float16*)Cout)[(size_t)(row + r) * N + col] = (_Float16)v;
                else
                    ((float*)Cout)[(size_t)(row + r) * N + col] = v;
            }
        }
    }
}

// ---------------------------------------------------------------------------
// MFMA flash attention — pipelined (T3/T4): K/V double-buffered in LDS,
// next tile's global_load_lds issued at the top of the current tile, counted
// s_waitcnt vmcnt(4) (never drains to 0 mid-loop), raw s_barrier with
// lgkmcnt(0)-only at the P-visibility barrier. P buffer is [64][64] with
// granule XOR-swizzle (byte granule ^ (row&7), same involution on write and
// read) so total LDS = 16K (K) + 16K (V) + 8K (P) = 40960 B -> 4 blocks/CU
// (grid gives exactly 4/CU). s_setprio(1) around both MFMA clusters (T5).
// ---------------------------------------------------------------------------
__global__ __launch_bounds__(256, 4)
void flash_attn_kernel(const _Float16* __restrict__ qkv,
                       const _Float16* __restrict__ vtg,
                       _Float16* __restrict__ out)
{
    const int qt = blockIdx.x;          // 0..31
    const int bh = blockIdx.y;          // 0..31
    const int b  = bh >> 4, h = bh & 15;
    const int t    = threadIdx.x;
    const int w    = t >> 6;
    const int lane = t & 63;
    const int quad = lane >> 4;
    const int l16  = lane & 15;
    const int sw   = l16 & 7;

    __shared__ __align__(16) _Float16 Ks [2][64 * 64];
    __shared__ __align__(16) _Float16 Vts[2][64 * 64];
    __shared__ __align__(16) _Float16 Ps [64 * 64];

    const int q0 = qt * 64;
    const size_t rstr = 3 * DIMM;
    const _Float16* qbase = qkv + (size_t)b * SEQ * rstr;

    // ---- Q fragments: register-resident for the whole k-loop
    f16x8 qf[4][2];
    #pragma unroll
    for (int qb = 0; qb < 4; qb++) {
        const _Float16* qrow = qbase + (size_t)(q0 + qb * 16 + l16) * rstr + h * HDIM;
        qf[qb][0] = *(const f16x8*)(qrow + quad * 8);
        qf[qb][1] = *(const f16x8*)(qrow + 32 + quad * 8);
    }

    f32x4 Oacc[4];
    #pragma unroll
    for (int i = 0; i < 4; i++) Oacc[i] = (f32x4){0.f, 0.f, 0.f, 0.f};
    float lrow[4] = {0.f, 0.f, 0.f, 0.f};

    // staging descriptors (two 16B segments each for K and Vt per thread)
    const int seg0 = t, seg1 = t + 256;
    const int r0 = seg0 >> 3, lb0 = (seg0 & 7) ^ (r0 & 7);
    const int r1 = seg1 >> 3, lb1 = (seg1 & 7) ^ (r1 & 7);
    const _Float16* gK0 = qbase + (size_t)r0 * rstr + DIMM + h * HDIM + lb0 * 8;
    const _Float16* gK1 = qbase + (size_t)r1 * rstr + DIMM + h * HDIM + lb1 * 8;
    const _Float16* gV0 = vtg + ((size_t)bh * 64 + r0) * SEQ + lb0 * 8;
    const _Float16* gV1 = vtg + ((size_t)bh * 64 + r1) * SEQ + lb1 * 8;

    const int kAbase = (16 * w + l16) * 64;
    const int pRbase = (16 * w + l16) * 64;
    // P-write physical granule (logical col 16w+4quad, row-XOR sw applied at store)
    const int pWg = (2 * w + (quad >> 1));
    const int pWo = (quad & 1) * 4;

    // ---- prologue: stage tile 0 into buffer 0
    gl_lds16(gK0, &Ks [0][seg0 * 8]);
    gl_lds16(gK1, &Ks [0][seg1 * 8]);
    gl_lds16(gV0, &Vts[0][seg0 * 8]);
    gl_lds16(gV1, &Vts[0][seg1 * 8]);

    #pragma unroll 2
    for (int k0 = 0; k0 < SEQ; k0 += 64) {
        const int cur = (k0 >> 6) & 1;
        const _Float16* KsC  = &Ks [cur][0];
        const _Float16* VtsC = &Vts[cur][0];

        // issue next tile's staging into the alternate buffers, then wait for
        // the CURRENT tile's 4 loads only (they are the oldest outstanding).
        if (k0 + 64 < SEQ) {
            const int nxt = cur ^ 1;
            gl_lds16(gK0 + (size_t)(k0 + 64) * rstr, &Ks [nxt][seg0 * 8]);
            gl_lds16(gK1 + (size_t)(k0 + 64) * rstr, &Ks [nxt][seg1 * 8]);
            gl_lds16(gV0 + (k0 + 64),                &Vts[nxt][seg0 * 8]);
            gl_lds16(gV1 + (k0 + 64),                &Vts[nxt][seg1 * 8]);
            asm volatile("s_waitcnt vmcnt(4)" ::: "memory");
        } else {
            asm volatile("s_waitcnt vmcnt(0)" ::: "memory");
        }
        __builtin_amdgcn_s_barrier();          // tile data visible block-wide
        asm volatile("" ::: "memory");

        // ---- S^T strip: keys [16w,16w+16) x 64 q  (MFMA cluster first)
        f16x8 kf0 = *(const f16x8*)(KsC + kAbase + ((0 + quad) ^ sw) * 8);
        f16x8 kf1 = *(const f16x8*)(KsC + kAbase + ((4 + quad) ^ sw) * 8);
        f32x4 sacc[4];
        __builtin_amdgcn_s_setprio(1);
        #pragma unroll
        for (int qb = 0; qb < 4; qb++) {
            f32x4 s = (f32x4){0.f, 0.f, 0.f, 0.f};
            s = __builtin_amdgcn_mfma_f32_16x16x32_f16(kf0, qf[qb][0], s, 0, 0, 0);
            s = __builtin_amdgcn_mfma_f32_16x16x32_f16(kf1, qf[qb][1], s, 0, 0, 0);
            sacc[qb] = s;
        }
        __builtin_amdgcn_s_setprio(0);

        // ---- softmax numerator + P store ([64][64], granule ^ (row&7))
        #pragma unroll
        for (int qb = 0; qb < 4; qb++) {
            float p0 = __expf(sacc[qb][0] * 0.125f);
            float p1 = __expf(sacc[qb][1] * 0.125f);
            float p2 = __expf(sacc[qb][2] * 0.125f);
            float p3 = __expf(sacc[qb][3] * 0.125f);
            lrow[qb] += (p0 + p1) + (p2 + p3);
            f16x4 pk;
            pk[0] = (_Float16)p0; pk[1] = (_Float16)p1;
            pk[2] = (_Float16)p2; pk[3] = (_Float16)p3;
            *(f16x4*)(Ps + (qb * 16 + l16) * 64 + (pWg ^ sw) * 8 + pWo) = pk;
        }
        asm volatile("s_waitcnt lgkmcnt(0)" ::: "memory");  // P writes drained
        __builtin_amdgcn_s_barrier();          // P visible; vmem stays in flight
        asm volatile("" ::: "memory");

        // ---- O += P · V^T : q-strip [16w,16w+16) x 64 d
        f16x8 pf0 = *(const f16x8*)(Ps + pRbase + ((0 + quad) ^ sw) * 8);
        f16x8 pf1 = *(const f16x8*)(Ps + pRbase + ((4 + quad) ^ sw) * 8);
        f16x8 vf[4][2];
        #pragma unroll
        for (int db = 0; db < 4; db++) {
            const int vrow = db * 16 + l16;
            vf[db][0] = *(const f16x8*)(VtsC + vrow * 64 + ((0 + quad) ^ sw) * 8);
            vf[db][1] = *(const f16x8*)(VtsC + vrow * 64 + ((4 + quad) ^ sw) * 8);
        }
        __builtin_amdgcn_s_setprio(1);
        #pragma unroll
        for (int db = 0; db < 4; db++) {
            Oacc[db] = __builtin_amdgcn_mfma_f32_16x16x32_f16(pf0, vf[db][0], Oacc[db], 0, 0, 0);
            Oacc[db] = __builtin_amdgcn_mfma_f32_16x16x32_f16(pf1, vf[db][1], Oacc[db], 0, 0, 0);
        }
        __builtin_amdgcn_s_setprio(0);
        __builtin_amdgcn_s_barrier();          // all cur-buffer/P reads done
        asm volatile("" ::: "memory");
    }

    // ---- softmax denominator: reduce over quads, then waves (via LDS)
    #pragma unroll
    for (int qb = 0; qb < 4; qb++) {
        lrow[qb] += __shfl_xor(lrow[qb], 16);
        lrow[qb] += __shfl_xor(lrow[qb], 32);
    }
    __syncthreads();                            // all PV done; Ks reusable
    float* lbuf = (float*)Ks;
    if (lane < 16) {
        #pragma unroll
        for (int qb = 0; qb < 4; qb++) lbuf[w * 64 + qb * 16 + lane] = lrow[qb];
    }
    __syncthreads();
    const int qloc = 16 * w + quad * 4;
    float lrec[4];
    #pragma unroll
    for (int r = 0; r < 4; r++) {
        const int q = qloc + r;
        lrec[r] = 1.f / (lbuf[q] + lbuf[64 + q] + lbuf[128 + q] + lbuf[192 + q]);
    }
    #pragma unroll
    for (int db = 0; db < 4; db++) {
        #pragma unroll
        for (int r = 0; r < 4; r++) {
            out[(size_t)(b * SEQ + q0 + qloc + r) * DIMM + h * HDIM + db * 16 + l16] =
                (_Float16)(Oacc[db][r] * lrec[r]);
        }
    }
}

// ---------------------------------------------------------------------------
extern "C" void kernel_launch(void* const* d_in, const int* in_sizes, int n_in,
                              void* d_out, int out_size, void* d_ws, size_t ws_size,
                              hipStream_t stream)
{
    const float* x    = (const float*)d_in[0];   // [2,2048,1024]
    const float* Wqkv = (const float*)d_in[1];   // [1024,3072]
    const float* bqkv = (const float*)d_in[2];   // [3072]
    const float* Wout = (const float*)d_in[3];   // [1024,1024]
    const float* bout = (const float*)d_in[4];   // [1024]
    float* out = (float*)d_out;                  // [2,2048,1024]

    _Float16* qkvh  = (_Float16*)d_ws;                   // 4096x3072
    _Float16* attnh = qkvh  + (size_t)ROWS * 3 * DIMM;   // 4096x1024
    _Float16* xh    = attnh + (size_t)ROWS * DIMM;       // 4096x1024
    _Float16* wqkvt = xh    + (size_t)ROWS * DIMM;       // 3072x1024
    _Float16* woutt = wqkvt + (size_t)3 * DIMM * DIMM;   // 1024x1024
    _Float16* vtg   = woutt + (size_t)DIMM * DIMM;       // 32 x 64 x 2048

    // 0) merged fp16 conversions (x, W_qkv^T, W_out^T)
    prep_kernel<<<3072, 256, 0, stream>>>(x, Wqkv, Wout, xh, wqkvt, woutt);
    // 1) qkv = x @ W_qkv + b_qkv   (fp16 out)
    {
        dim3 grid(3 * DIMM / 128, ROWS / 128);
        hgemm_bias_kernel<1><<<grid, 256, 0, stream>>>(xh, wqkvt, bqkv, qkvh, 3 * DIMM, DIMM);
    }
    // 1b) global V transpose
    {
        dim3 grid(SEQ / 64, BATCH * NHEADS);
        vtranspose_kernel<<<grid, 256, 0, stream>>>(qkvh, vtg);
    }
    // 2) attention -> attnh (fp16)
    {
        dim3 grid(SEQ / 64, BATCH * NHEADS);
        flash_attn_kernel<<<grid, 256, 0, stream>>>(qkvh, vtg, attnh);
    }
    // 3) out = attn @ W_out + b_out  (fp32 out)
    {
        dim3 grid(DIMM / 128, ROWS / 128);
        hgemm_bias_kernel<0><<<grid, 256, 0, stream>>>(attnh, woutt, bout, out, DIMM, DIMM);
    }
}

// Round 2
// 212.155 us; speedup vs baseline: 1.0829x; 1.0829x over previous
//
#include <hip/hip_runtime.h>
#include <math.h>

// Problem constants (AttentionLikeModel_75531294867774)
#define DIMM    1024
#define NHEADS  16
#define HDIM    64
#define BATCH   2
#define SEQ     2048
#define ROWS    (BATCH*SEQ)   // 4096

typedef _Float16 f16x8 __attribute__((ext_vector_type(8)));
typedef _Float16 f16x4 __attribute__((ext_vector_type(4)));
typedef float    f32x4 __attribute__((ext_vector_type(4)));

__device__ inline void gl_lds16(const void* g, void* l) {
    __builtin_amdgcn_global_load_lds(
        (const __attribute__((address_space(1))) void*)g,
        (__attribute__((address_space(3))) void*)l, 16, 0, 0);
}

// ---------------------------------------------------------------------------
// Merged prep: blocks [0,2048) cvt x -> fp16; [2048,2816) W_qkv^T; [2816,3072) W_out^T
// ---------------------------------------------------------------------------
__device__ void tcvt64(const float* __restrict__ in, _Float16* __restrict__ out,
                       int K, int N, int k0, int n0, float (*tile)[65], int t)
{
    {
        const int c4 = (t & 15) * 4;
        const int r  = t >> 4;
        #pragma unroll
        for (int i = 0; i < 4; i++) {
            const int rr = r + 16 * i;
            float4 v = *(const float4*)(in + (size_t)(k0 + rr) * N + n0 + c4);
            tile[rr][c4] = v.x; tile[rr][c4 + 1] = v.y;
            tile[rr][c4 + 2] = v.z; tile[rr][c4 + 3] = v.w;
        }
    }
    __syncthreads();
    #pragma unroll
    for (int i = 0; i < 2; i++) {
        const int seg = t + 256 * i;
        const int n   = seg >> 3;
        const int kc  = (seg & 7) * 8;
        f16x8 o;
        #pragma unroll
        for (int j = 0; j < 8; j++) o[j] = (_Float16)tile[kc + j][n];
        *(f16x8*)(out + (size_t)(n0 + n) * K + k0 + kc) = o;
    }
}

__global__ __launch_bounds__(256)
void prep_kernel(const float* __restrict__ x, const float* __restrict__ Wqkv,
                 const float* __restrict__ Wout, _Float16* __restrict__ xh,
                 _Float16* __restrict__ wqkvt, _Float16* __restrict__ woutt)
{
    __shared__ float tile[64][65];
    const int bx = blockIdx.x;
    const int t  = threadIdx.x;
    if (bx < 2048) {                       // cvt x (4096x1024 / 8 / 256 = 2048 blocks)
        const int i = bx * 256 + t;
        const float4 a = *(const float4*)(x + (size_t)i * 8);
        const float4 b = *(const float4*)(x + (size_t)i * 8 + 4);
        f16x8 o;
        o[0] = (_Float16)a.x; o[1] = (_Float16)a.y; o[2] = (_Float16)a.z; o[3] = (_Float16)a.w;
        o[4] = (_Float16)b.x; o[5] = (_Float16)b.y; o[6] = (_Float16)b.z; o[7] = (_Float16)b.w;
        *(f16x8*)(xh + (size_t)i * 8) = o;
    } else if (bx < 2816) {                // W_qkv^T: grid (48,16)
        const int id = bx - 2048;
        const int gx = id % 48, gy = id / 48;
        tcvt64(Wqkv, wqkvt, DIMM, 3 * DIMM, gy * 64, gx * 64, tile, t);
    } else {                               // W_out^T: grid (16,16)
        const int id = bx - 2816;
        const int gx = id & 15, gy = id >> 4;
        tcvt64(Wout, woutt, DIMM, DIMM, gy * 64, gx * 64, tile, t);
    }
}

// ---------------------------------------------------------------------------
// V-transpose: qkvh V-third [b][key][h*64+d] -> vt[bh][d][key] (fp16)
// ---------------------------------------------------------------------------
__global__ __launch_bounds__(256)
void vtranspose_kernel(const _Float16* __restrict__ qkvh, _Float16* __restrict__ vt)
{
    __shared__ _Float16 tile[64][72];
    const int kt = blockIdx.x;
    const int bh = blockIdx.y;
    const int b  = bh >> 4, h = bh & 15;
    const int t  = threadIdx.x;
    {
        const int key = t >> 2, c4 = (t & 3) * 16;
        const _Float16* src = qkvh + ((size_t)(b * SEQ + kt * 64 + key)) * (3 * DIMM)
                              + 2 * DIMM + h * HDIM + c4;
        f16x8 v0 = *(const f16x8*)src;
        f16x8 v1 = *(const f16x8*)(src + 8);
        #pragma unroll
        for (int j = 0; j < 8; j++) {
            tile[c4 + j][key]     = v0[j];
            tile[c4 + 8 + j][key] = v1[j];
        }
    }
    __syncthreads();
    {
        const int d = t >> 2, k4 = (t & 3) * 16;
        f16x8 o0, o1;
        #pragma unroll
        for (int j = 0; j < 8; j++) { o0[j] = tile[d][k4 + j]; o1[j] = tile[d][k4 + 8 + j]; }
        _Float16* dst = vt + ((size_t)bh * 64 + d) * SEQ + kt * 64 + k4;
        *(f16x8*)dst       = o0;
        *(f16x8*)(dst + 8) = o1;
    }
}

// ---------------------------------------------------------------------------
// HGEMM + bias, BK=64 (m97 config): 128x128x64 tile, 32 MFMA per barrier pair.
// ---------------------------------------------------------------------------
template<int OUT_F16>
__global__ __launch_bounds__(256)
void hgemm_bias_kernel(const _Float16* __restrict__ A, const _Float16* __restrict__ Bt,
                       const float* __restrict__ bias, void* __restrict__ Cout,
                       int N, int K)
{
    __shared__ _Float16 As[128 * 64];
    __shared__ _Float16 Bs[128 * 64];

    const int t    = threadIdx.x;
    const int w    = t >> 6, lane = t & 63;
    const int quad = lane >> 4, l16 = lane & 15;
    const int wr   = w >> 1, wc = w & 1;
    const int row0 = blockIdx.y * 128, col0 = blockIdx.x * 128;
    const int sw   = l16 & 7;

    f32x4 acc[4][4];
    #pragma unroll
    for (int i = 0; i < 4; i++)
        #pragma unroll
        for (int j = 0; j < 4; j++)
            #pragma unroll
            for (int r = 0; r < 4; r++) acc[i][j][r] = 0.f;

    const _Float16* gA[4];
    const _Float16* gB[4];
    int lofs[4];
    #pragma unroll
    for (int j = 0; j < 4; j++) {
        const int s   = t + 256 * j;
        const int row = s >> 3;
        const int kb  = (s & 7) ^ (row & 7);
        gA[j] = A  + (size_t)(row0 + row) * K + kb * 8;
        gB[j] = Bt + (size_t)(col0 + row) * K + kb * 8;
        lofs[j] = s * 8;
    }

    const int niter = K >> 6;
    #pragma unroll 1
    for (int it = 0; it < niter; it++) {
        __syncthreads();
        #pragma unroll
        for (int j = 0; j < 4; j++) gl_lds16(gA[j], As + lofs[j]);
        #pragma unroll
        for (int j = 0; j < 4; j++) gl_lds16(gB[j], Bs + lofs[j]);
        #pragma unroll
        for (int j = 0; j < 4; j++) { gA[j] += 64; gB[j] += 64; }
        __syncthreads();

        f16x8 af[4][2], bf[4][2];
        #pragma unroll
        for (int i = 0; i < 4; i++) {
            const int arow = wr * 64 + i * 16 + l16;
            const int brow = wc * 64 + i * 16 + l16;
            #pragma unroll
            for (int hh = 0; hh < 2; hh++) {
                af[i][hh] = *(const f16x8*)(As + (arow * 8 + ((hh * 4 + quad) ^ sw)) * 8);
                bf[i][hh] = *(const f16x8*)(Bs + (brow * 8 + ((hh * 4 + quad) ^ sw)) * 8);
            }
        }
        #pragma unroll
        for (int i = 0; i < 4; i++)
            #pragma unroll
            for (int j = 0; j < 4; j++) {
                acc[i][j] = __builtin_amdgcn_mfma_f32_16x16x32_f16(af[i][0], bf[j][0], acc[i][j], 0, 0, 0);
                acc[i][j] = __builtin_amdgcn_mfma_f32_16x16x32_f16(af[i][1], bf[j][1], acc[i][j], 0, 0, 0);
            }
    }

    #pragma unroll
    for (int j = 0; j < 4; j++) {
        const int col = col0 + wc * 64 + j * 16 + l16;
        const float bv = bias[col];
        #pragma unroll
        for (int i = 0; i < 4; i++) {
            const int row = row0 + wr * 64 + i * 16 + quad * 4;
            #pragma unroll
            for (int r = 0; r < 4; r++) {
                const float v = acc[i][j][r] + bv;
                if (OUT_F16)
                    ((_Float16*)Cout)[(size_t)(row + r) * N + col] = (_Float16)v;
                else
                    ((float*)Cout)[(size_t)(row + r) * N + col] = v;
            }
        }
    }
}

// ---------------------------------------------------------------------------
// MFMA flash attention — pipelined (T3/T4) with ROUND-0 register discipline.
// K/V double-buffered in LDS; next tile's global_load_lds issued at the top,
// counted s_waitcnt vmcnt(4) (never drains mid-loop); P-visibility barrier is
// lgkmcnt(0)-only so prefetch stays in flight. Softmax stays interleaved
// per-qb (sacc consumed immediately) and PV reads vf per-db (2 frags live at
// a time) to keep peak VGPR pressure at round-0 levels (no scratch).
// P buffer [64][64] granule-XOR swizzled (byte granule ^ (row&7), same
// involution write & read): LDS total = 16K (K) + 16K (V) + 8K (P) = 40960 B
// -> 4 blocks/CU.
// ---------------------------------------------------------------------------
__global__ __launch_bounds__(256, 4)
void flash_attn_kernel(const _Float16* __restrict__ qkv,
                       const _Float16* __restrict__ vtg,
                       _Float16* __restrict__ out)
{
    const int qt = blockIdx.x;          // 0..31
    const int bh = blockIdx.y;          // 0..31
    const int b  = bh >> 4, h = bh & 15;
    const int t    = threadIdx.x;
    const int w    = t >> 6;
    const int lane = t & 63;
    const int quad = lane >> 4;
    const int l16  = lane & 15;
    const int sw   = l16 & 7;

    __shared__ __align__(16) _Float16 Ks [2][64 * 64];
    __shared__ __align__(16) _Float16 Vts[2][64 * 64];
    __shared__ __align__(16) _Float16 Ps [64 * 64];

    const int q0 = qt * 64;
    const size_t rstr = 3 * DIMM;
    const _Float16* qbase = qkv + (size_t)b * SEQ * rstr;

    // ---- Q fragments: register-resident for the whole k-loop
    f16x8 qf[4][2];
    #pragma unroll
    for (int qb = 0; qb < 4; qb++) {
        const _Float16* qrow = qbase + (size_t)(q0 + qb * 16 + l16) * rstr + h * HDIM;
        qf[qb][0] = *(const f16x8*)(qrow + quad * 8);
        qf[qb][1] = *(const f16x8*)(qrow + 32 + quad * 8);
    }

    f32x4 Oacc[4];
    #pragma unroll
    for (int i = 0; i < 4; i++) Oacc[i] = (f32x4){0.f, 0.f, 0.f, 0.f};
    float lrow[4] = {0.f, 0.f, 0.f, 0.f};

    // staging descriptors (two 16B segments each for K and Vt per thread)
    const int seg0 = t, seg1 = t + 256;
    const int r0 = seg0 >> 3, lb0 = (seg0 & 7) ^ (r0 & 7);
    const int r1 = seg1 >> 3, lb1 = (seg1 & 7) ^ (r1 & 7);
    const _Float16* gK0 = qbase + (size_t)r0 * rstr + DIMM + h * HDIM + lb0 * 8;
    const _Float16* gK1 = qbase + (size_t)r1 * rstr + DIMM + h * HDIM + lb1 * 8;
    const _Float16* gV0 = vtg + ((size_t)bh * 64 + r0) * SEQ + lb0 * 8;
    const _Float16* gV1 = vtg + ((size_t)bh * 64 + r1) * SEQ + lb1 * 8;

    const int kAbase = (16 * w + l16) * 64;
    const int pRbase = (16 * w + l16) * 64;
    // P-write physical granule (logical col 16w+4quad, row-XOR sw applied at store)
    const int pWg = (2 * w + (quad >> 1));
    const int pWo = (quad & 1) * 4;

    // ---- prologue: stage tile 0 into buffer 0
    gl_lds16(gK0, &Ks [0][seg0 * 8]);
    gl_lds16(gK1, &Ks [0][seg1 * 8]);
    gl_lds16(gV0, &Vts[0][seg0 * 8]);
    gl_lds16(gV1, &Vts[0][seg1 * 8]);

    #pragma unroll 2
    for (int k0 = 0; k0 < SEQ; k0 += 64) {
        const int cur = (k0 >> 6) & 1;
        const _Float16* KsC  = &Ks [cur][0];
        const _Float16* VtsC = &Vts[cur][0];

        // issue next tile's staging into the alternate buffers, then wait for
        // the CURRENT tile's 4 loads only (they are the oldest outstanding).
        if (k0 + 64 < SEQ) {
            const int nxt = cur ^ 1;
            gl_lds16(gK0 + (size_t)(k0 + 64) * rstr, &Ks [nxt][seg0 * 8]);
            gl_lds16(gK1 + (size_t)(k0 + 64) * rstr, &Ks [nxt][seg1 * 8]);
            gl_lds16(gV0 + (k0 + 64),                &Vts[nxt][seg0 * 8]);
            gl_lds16(gV1 + (k0 + 64),                &Vts[nxt][seg1 * 8]);
            asm volatile("s_waitcnt vmcnt(4)" ::: "memory");
        } else {
            asm volatile("s_waitcnt vmcnt(0)" ::: "memory");
        }
        __builtin_amdgcn_s_barrier();          // tile data visible block-wide
        asm volatile("" ::: "memory");

        // ---- S^T strip: keys [16w,16w+16) x 64 q (round-0 interleave:
        //      each qb's scores consumed immediately -> low live range)
        f16x8 kf0 = *(const f16x8*)(KsC + kAbase + ((0 + quad) ^ sw) * 8);
        f16x8 kf1 = *(const f16x8*)(KsC + kAbase + ((4 + quad) ^ sw) * 8);
        #pragma unroll
        for (int qb = 0; qb < 4; qb++) {
            f32x4 s = (f32x4){0.f, 0.f, 0.f, 0.f};
            s = __builtin_amdgcn_mfma_f32_16x16x32_f16(kf0, qf[qb][0], s, 0, 0, 0);
            s = __builtin_amdgcn_mfma_f32_16x16x32_f16(kf1, qf[qb][1], s, 0, 0, 0);
            float p0 = __expf(s[0] * 0.125f);
            float p1 = __expf(s[1] * 0.125f);
            float p2 = __expf(s[2] * 0.125f);
            float p3 = __expf(s[3] * 0.125f);
            lrow[qb] += (p0 + p1) + (p2 + p3);
            f16x4 pk;
            pk[0] = (_Float16)p0; pk[1] = (_Float16)p1;
            pk[2] = (_Float16)p2; pk[3] = (_Float16)p3;
            *(f16x4*)(Ps + (qb * 16 + l16) * 64 + (pWg ^ sw) * 8 + pWo) = pk;
        }
        asm volatile("s_waitcnt lgkmcnt(0)" ::: "memory");  // P writes drained
        __builtin_amdgcn_s_barrier();          // P visible; vmem stays in flight
        asm volatile("" ::: "memory");

        // ---- O += P · V^T : q-strip [16w,16w+16) x 64 d (per-db vf reads)
        f16x8 pf0 = *(const f16x8*)(Ps + pRbase + ((0 + quad) ^ sw) * 8);
        f16x8 pf1 = *(const f16x8*)(Ps + pRbase + ((4 + quad) ^ sw) * 8);
        #pragma unroll
        for (int db = 0; db < 4; db++) {
            const int vrow = db * 16 + l16;
            f16x8 vf0 = *(const f16x8*)(VtsC + vrow * 64 + ((0 + quad) ^ sw) * 8);
            f16x8 vf1 = *(const f16x8*)(VtsC + vrow * 64 + ((4 + quad) ^ sw) * 8);
            Oacc[db] = __builtin_amdgcn_mfma_f32_16x16x32_f16(pf0, vf0, Oacc[db], 0, 0, 0);
            Oacc[db] = __builtin_amdgcn_mfma_f32_16x16x32_f16(pf1, vf1, Oacc[db], 0, 0, 0);
        }
        __builtin_amdgcn_s_barrier();          // all cur-buffer/P reads done
        asm volatile("" ::: "memory");
    }

    // ---- softmax denominator: reduce over quads, then waves (via LDS)
    #pragma unroll
    for (int qb = 0; qb < 4; qb++) {
        lrow[qb] += __shfl_xor(lrow[qb], 16);
        lrow[qb] += __shfl_xor(lrow[qb], 32);
    }
    __syncthreads();                            // all PV done; Ks reusable
    float* lbuf = (float*)Ks;
    if (lane < 16) {
        #pragma unroll
        for (int qb = 0; qb < 4; qb++) lbuf[w * 64 + qb * 16 + lane] = lrow[qb];
    }
    __syncthreads();
    const int qloc = 16 * w + quad * 4;
    float lrec[4];
    #pragma unroll
    for (int r = 0; r < 4; r++) {
        const int q = qloc + r;
        lrec[r] = 1.f / (lbuf[q] + lbuf[64 + q] + lbuf[128 + q] + lbuf[192 + q]);
    }
    #pragma unroll
    for (int db = 0; db < 4; db++) {
        #pragma unroll
        for (int r = 0; r < 4; r++) {
            out[(size_t)(b * SEQ + q0 + qloc + r) * DIMM + h * HDIM + db * 16 + l16] =
                (_Float16)(Oacc[db][r] * lrec[r]);
        }
    }
}

// ---------------------------------------------------------------------------
extern "C" void kernel_launch(void* const* d_in, const int* in_sizes, int n_in,
                              void* d_out, int out_size, void* d_ws, size_t ws_size,
                              hipStream_t stream)
{
    const float* x    = (const float*)d_in[0];   // [2,2048,1024]
    const float* Wqkv = (const float*)d_in[1];   // [1024,3072]
    const float* bqkv = (const float*)d_in[2];   // [3072]
    const float* Wout = (const float*)d_in[3];   // [1024,1024]
    const float* bout = (const float*)d_in[4];   // [1024]
    float* out = (float*)d_out;                  // [2,2048,1024]

    _Float16* qkvh  = (_Float16*)d_ws;                   // 4096x3072
    _Float16* attnh = qkvh  + (size_t)ROWS * 3 * DIMM;   // 4096x1024
    _Float16* xh    = attnh + (size_t)ROWS * DIMM;       // 4096x1024
    _Float16* wqkvt = xh    + (size_t)ROWS * DIMM;       // 3072x1024
    _Float16* woutt = wqkvt + (size_t)3 * DIMM * DIMM;   // 1024x1024
    _Float16* vtg   = woutt + (size_t)DIMM * DIMM;       // 32 x 64 x 2048

    // 0) merged fp16 conversions (x, W_qkv^T, W_out^T)
    prep_kernel<<<3072, 256, 0, stream>>>(x, Wqkv, Wout, xh, wqkvt, woutt);
    // 1) qkv = x @ W_qkv + b_qkv   (fp16 out)
    {
        dim3 grid(3 * DIMM / 128, ROWS / 128);
        hgemm_bias_kernel<1><<<grid, 256, 0, stream>>>(xh, wqkvt, bqkv, qkvh, 3 * DIMM, DIMM);
    }
    // 1b) global V transpose
    {
        dim3 grid(SEQ / 64, BATCH * NHEADS);
        vtranspose_kernel<<<grid, 256, 0, stream>>>(qkvh, vtg);
    }
    // 2) attention -> attnh (fp16)
    {
        dim3 grid(SEQ / 64, BATCH * NHEADS);
        flash_attn_kernel<<<grid, 256, 0, stream>>>(qkvh, vtg, attnh);
    }
    // 3) out = attn @ W_out + b_out  (fp32 out)
    {
        dim3 grid(DIMM / 128, ROWS / 128);
        hgemm_bias_kernel<0><<<grid, 256, 0, stream>>>(attnh, woutt, bout, out, DIMM, DIMM);
    }
}

// Round 4
// 204.739 us; speedup vs baseline: 1.1221x; 1.0362x over previous
//
#include <hip/hip_runtime.h>
#include <math.h>

// Problem constants (AttentionLikeModel_75531294867774)
#define DIMM    1024
#define NHEADS  16
#define HDIM    64
#define BATCH   2
#define SEQ     2048
#define ROWS    (BATCH*SEQ)   // 4096

typedef _Float16 f16x8 __attribute__((ext_vector_type(8)));
typedef _Float16 f16x4 __attribute__((ext_vector_type(4)));
typedef float    f32x4 __attribute__((ext_vector_type(4)));
typedef float    f32x16 __attribute__((ext_vector_type(16)));

__device__ inline void gl_lds16(const void* g, void* l) {
    __builtin_amdgcn_global_load_lds(
        (const __attribute__((address_space(1))) void*)g,
        (__attribute__((address_space(3))) void*)l, 16, 0, 0);
}

static __device__ inline unsigned packh(_Float16 a, _Float16 b) {
    unsigned short ua = __builtin_bit_cast(unsigned short, a);
    unsigned short ub = __builtin_bit_cast(unsigned short, b);
    return (unsigned)ua | ((unsigned)ub << 16);
}
static __device__ inline f16x8 mkfrag(unsigned a, unsigned b, unsigned c, unsigned d) {
    union { unsigned u[4]; f16x8 v; } x;
    x.u[0] = a; x.u[1] = b; x.u[2] = c; x.u[3] = d;
    return x.v;
}

// ---------------------------------------------------------------------------
// Merged prep: blocks [0,2048) cvt x -> fp16; [2048,2816) W_qkv^T; [2816,3072) W_out^T
// ---------------------------------------------------------------------------
__device__ void tcvt64(const float* __restrict__ in, _Float16* __restrict__ out,
                       int K, int N, int k0, int n0, float (*tile)[65], int t)
{
    {
        const int c4 = (t & 15) * 4;
        const int r  = t >> 4;
        #pragma unroll
        for (int i = 0; i < 4; i++) {
            const int rr = r + 16 * i;
            float4 v = *(const float4*)(in + (size_t)(k0 + rr) * N + n0 + c4);
            tile[rr][c4] = v.x; tile[rr][c4 + 1] = v.y;
            tile[rr][c4 + 2] = v.z; tile[rr][c4 + 3] = v.w;
        }
    }
    __syncthreads();
    #pragma unroll
    for (int i = 0; i < 2; i++) {
        const int seg = t + 256 * i;
        const int n   = seg >> 3;
        const int kc  = (seg & 7) * 8;
        f16x8 o;
        #pragma unroll
        for (int j = 0; j < 8; j++) o[j] = (_Float16)tile[kc + j][n];
        *(f16x8*)(out + (size_t)(n0 + n) * K + k0 + kc) = o;
    }
}

__global__ __launch_bounds__(256)
void prep_kernel(const float* __restrict__ x, const float* __restrict__ Wqkv,
                 const float* __restrict__ Wout, _Float16* __restrict__ xh,
                 _Float16* __restrict__ wqkvt, _Float16* __restrict__ woutt)
{
    __shared__ float tile[64][65];
    const int bx = blockIdx.x;
    const int t  = threadIdx.x;
    if (bx < 2048) {                       // cvt x (4096x1024 / 8 / 256 = 2048 blocks)
        const int i = bx * 256 + t;
        const float4 a = *(const float4*)(x + (size_t)i * 8);
        const float4 b = *(const float4*)(x + (size_t)i * 8 + 4);
        f16x8 o;
        o[0] = (_Float16)a.x; o[1] = (_Float16)a.y; o[2] = (_Float16)a.z; o[3] = (_Float16)a.w;
        o[4] = (_Float16)b.x; o[5] = (_Float16)b.y; o[6] = (_Float16)b.z; o[7] = (_Float16)b.w;
        *(f16x8*)(xh + (size_t)i * 8) = o;
    } else if (bx < 2816) {                // W_qkv^T: grid (48,16)
        const int id = bx - 2048;
        const int gx = id % 48, gy = id / 48;
        tcvt64(Wqkv, wqkvt, DIMM, 3 * DIMM, gy * 64, gx * 64, tile, t);
    } else {                               // W_out^T: grid (16,16)
        const int id = bx - 2816;
        const int gx = id & 15, gy = id >> 4;
        tcvt64(Wout, woutt, DIMM, DIMM, gy * 64, gx * 64, tile, t);
    }
}

// ---------------------------------------------------------------------------
// V-transpose: qkvh V-third [b][key][h*64+d] -> vt[bh][d][key] (fp16)
// ---------------------------------------------------------------------------
__global__ __launch_bounds__(256)
void vtranspose_kernel(const _Float16* __restrict__ qkvh, _Float16* __restrict__ vt)
{
    __shared__ _Float16 tile[64][72];
    const int kt = blockIdx.x;
    const int bh = blockIdx.y;
    const int b  = bh >> 4, h = bh & 15;
    const int t  = threadIdx.x;
    {
        const int key = t >> 2, c4 = (t & 3) * 16;
        const _Float16* src = qkvh + ((size_t)(b * SEQ + kt * 64 + key)) * (3 * DIMM)
                              + 2 * DIMM + h * HDIM + c4;
        f16x8 v0 = *(const f16x8*)src;
        f16x8 v1 = *(const f16x8*)(src + 8);
        #pragma unroll
        for (int j = 0; j < 8; j++) {
            tile[c4 + j][key]     = v0[j];
            tile[c4 + 8 + j][key] = v1[j];
        }
    }
    __syncthreads();
    {
        const int d = t >> 2, k4 = (t & 3) * 16;
        f16x8 o0, o1;
        #pragma unroll
        for (int j = 0; j < 8; j++) { o0[j] = tile[d][k4 + j]; o1[j] = tile[d][k4 + 8 + j]; }
        _Float16* dst = vt + ((size_t)bh * 64 + d) * SEQ + kt * 64 + k4;
        *(f16x8*)dst       = o0;
        *(f16x8*)(dst + 8) = o1;
    }
}

// ---------------------------------------------------------------------------
// HGEMM + bias, BK=64 (m97 config): 128x128x64 tile, 32 MFMA per barrier pair.
// ---------------------------------------------------------------------------
template<int OUT_F16>
__global__ __launch_bounds__(256)
void hgemm_bias_kernel(const _Float16* __restrict__ A, const _Float16* __restrict__ Bt,
                       const float* __restrict__ bias, void* __restrict__ Cout,
                       int N, int K)
{
    __shared__ _Float16 As[128 * 64];
    __shared__ _Float16 Bs[128 * 64];

    const int t    = threadIdx.x;
    const int w    = t >> 6, lane = t & 63;
    const int quad = lane >> 4, l16 = lane & 15;
    const int wr   = w >> 1, wc = w & 1;
    const int row0 = blockIdx.y * 128, col0 = blockIdx.x * 128;
    const int sw   = l16 & 7;

    f32x4 acc[4][4];
    #pragma unroll
    for (int i = 0; i < 4; i++)
        #pragma unroll
        for (int j = 0; j < 4; j++)
            #pragma unroll
            for (int r = 0; r < 4; r++) acc[i][j][r] = 0.f;

    const _Float16* gA[4];
    const _Float16* gB[4];
    int lofs[4];
    #pragma unroll
    for (int j = 0; j < 4; j++) {
        const int s   = t + 256 * j;
        const int row = s >> 3;
        const int kb  = (s & 7) ^ (row & 7);
        gA[j] = A  + (size_t)(row0 + row) * K + kb * 8;
        gB[j] = Bt + (size_t)(col0 + row) * K + kb * 8;
        lofs[j] = s * 8;
    }

    const int niter = K >> 6;
    #pragma unroll 1
    for (int it = 0; it < niter; it++) {
        __syncthreads();
        #pragma unroll
        for (int j = 0; j < 4; j++) gl_lds16(gA[j], As + lofs[j]);
        #pragma unroll
        for (int j = 0; j < 4; j++) gl_lds16(gB[j], Bs + lofs[j]);
        #pragma unroll
        for (int j = 0; j < 4; j++) { gA[j] += 64; gB[j] += 64; }
        __syncthreads();

        f16x8 af[4][2], bf[4][2];
        #pragma unroll
        for (int i = 0; i < 4; i++) {
            const int arow = wr * 64 + i * 16 + l16;
            const int brow = wc * 64 + i * 16 + l16;
            #pragma unroll
            for (int hh = 0; hh < 2; hh++) {
                af[i][hh] = *(const f16x8*)(As + (arow * 8 + ((hh * 4 + quad) ^ sw)) * 8);
                bf[i][hh] = *(const f16x8*)(Bs + (brow * 8 + ((hh * 4 + quad) ^ sw)) * 8);
            }
        }
        #pragma unroll
        for (int i = 0; i < 4; i++)
            #pragma unroll
            for (int j = 0; j < 4; j++) {
                acc[i][j] = __builtin_amdgcn_mfma_f32_16x16x32_f16(af[i][0], bf[j][0], acc[i][j], 0, 0, 0);
                acc[i][j] = __builtin_amdgcn_mfma_f32_16x16x32_f16(af[i][1], bf[j][1], acc[i][j], 0, 0, 0);
            }
    }

    #pragma unroll
    for (int j = 0; j < 4; j++) {
        const int col = col0 + wc * 64 + j * 16 + l16;
        const float bv = bias[col];
        #pragma unroll
        for (int i = 0; i < 4; i++) {
            const int row = row0 + wr * 64 + i * 16 + quad * 4;
            #pragma unroll
            for (int r = 0; r < 4; r++) {
                const float v = acc[i][j][r] + bv;
                if (OUT_F16)
                    ((_Float16*)Cout)[(size_t)(row + r) * N + col] = (_Float16)v;
                else
                    ((float*)Cout)[(size_t)(row + r) * N + col] = v;
            }
        }
    }
}

// ---------------------------------------------------------------------------
// MFMA flash attention — in-register P (32x32x16 MFMA), RACE-FREE-BY-
// CONSTRUCTION sync. With P in registers a tile has ONLY reads of buf[cur];
// the prefetch DMA ONLY writes buf[nxt]; so ONE full __syncthreads() per tile
// enforces everything: it drains each wave's DMAs (buf[cur] valid) and all
// LDS reads of buf[nxt] from tile t-1 (safe to overwrite). No in-flight vmem
// crosses any barrier; no ordering needed inside the tile window, so compiler
// scheduling cannot introduce a race. Prefetch issued mid-tile (after QK^T)
// -> DMA latency overlaps exp/pack/shfl/PV (~2/3 of the tile).
// Per tile per wave: 8 ds_read_b128, 16 bpermute-equiv (shfl), 0 LDS writes,
// 1 barrier. Denominator uses fp16-ROUNDED P for num/den consistency.
// LDS = 32 KB -> 4 blocks/CU.
// ---------------------------------------------------------------------------
__global__ __launch_bounds__(256, 4)
void flash_attn_kernel(const _Float16* __restrict__ qkv,
                       const _Float16* __restrict__ vtg,
                       _Float16* __restrict__ out)
{
    const int qt = blockIdx.x;          // 0..31
    const int bh = blockIdx.y;          // 0..31
    const int b  = bh >> 4, hd = bh & 15;
    const int t    = threadIdx.x;
    const int w    = t >> 6;
    const int lane = t & 63;
    const int qg   = w >> 1;            // q-group (32 rows)
    const int kh   = w & 1;             // key-half (32 keys)
    const int l31  = lane & 31;
    const int hf   = lane >> 5;         // lane half
    const int l7   = lane & 7;

    __shared__ __align__(16) _Float16 Ks [2][64 * 64];
    __shared__ __align__(16) _Float16 Vts[2][64 * 64];

    const int q0 = qt * 64;
    const size_t rstr = 3 * DIMM;
    const _Float16* qbase = qkv + (size_t)b * SEQ * rstr;

    // ---- Q B-fragments (register-resident, unscaled; 0.125 applied on f32 scores)
    // B[k = d][col = q]: lane holds d = dd*16 + hf*8 + j, q = qg*32 + l31.
    f16x8 qf[4];
    {
        const _Float16* qrow = qbase + (size_t)(q0 + qg * 32 + l31) * rstr + hd * HDIM;
        #pragma unroll
        for (int dd = 0; dd < 4; dd++)
            qf[dd] = *(const f16x8*)(qrow + dd * 16 + hf * 8);
    }

    f32x16 Oacc[2];
    #pragma unroll
    for (int dh = 0; dh < 2; dh++)
        #pragma unroll
        for (int r = 0; r < 16; r++) Oacc[dh][r] = 0.f;
    float lrow = 0.f;

    // staging descriptors (two 16B segments each for K and Vt per thread)
    const int seg0 = t, seg1 = t + 256;
    const int r0 = seg0 >> 3, lb0 = (seg0 & 7) ^ (r0 & 7);
    const int r1 = seg1 >> 3, lb1 = (seg1 & 7) ^ (r1 & 7);
    const _Float16* gK0 = qbase + (size_t)r0 * rstr + DIMM + hd * HDIM + lb0 * 8;
    const _Float16* gK1 = qbase + (size_t)r1 * rstr + DIMM + hd * HDIM + lb1 * 8;
    const _Float16* gV0 = vtg + ((size_t)bh * 64 + r0) * SEQ + lb0 * 8;
    const _Float16* gV1 = vtg + ((size_t)bh * 64 + r1) * SEQ + lb1 * 8;

    // ---- prologue: stage tile 0 into buffer 0
    gl_lds16(gK0, &Ks [0][seg0 * 8]);
    gl_lds16(gK1, &Ks [0][seg1 * 8]);
    gl_lds16(gV0, &Vts[0][seg0 * 8]);
    gl_lds16(gV1, &Vts[0][seg1 * 8]);

    #pragma unroll 2
    for (int k0 = 0; k0 < SEQ; k0 += 64) {
        const int cur = (k0 >> 6) & 1;
        const _Float16* KsC  = &Ks [cur][0];
        const _Float16* VtsC = &Vts[cur][0];

        // ONE barrier per tile: drains this wave's DMAs (buf[cur] complete for
        // all waves after join) AND all waves' LDS reads of buf[cur^1] (t-1).
        __syncthreads();

        // ---- QK^T: S^T[32 keys (kh)][32 q (qg)], K-dim = 64 d in 4 slices.
        // A[row = key = kh*32+l31][k = dd*16 + hf*8 + j] from swizzled Ks.
        f32x16 sacc;
        #pragma unroll
        for (int r = 0; r < 16; r++) sacc[r] = 0.f;
        #pragma unroll
        for (int dd = 0; dd < 4; dd++) {
            f16x8 kf = *(const f16x8*)(KsC + (kh * 32 + l31) * 64 + (((dd * 2 + hf) ^ l7) * 8));
            sacc = __builtin_amdgcn_mfma_f32_32x32x16_f16(kf, qf[dd], sacc, 0, 0, 0);
        }

        // ---- prefetch next tile into buf[nxt] (not read this tile; latency
        // overlaps the exp/pack/shfl/PV below; drained at next __syncthreads)
        if (k0 + 64 < SEQ) {
            const int nxt = cur ^ 1;
            gl_lds16(gK0 + (size_t)(k0 + 64) * rstr, &Ks [nxt][seg0 * 8]);
            gl_lds16(gK1 + (size_t)(k0 + 64) * rstr, &Ks [nxt][seg1 * 8]);
            gl_lds16(gV0 + (k0 + 64),                &Vts[nxt][seg0 * 8]);
            gl_lds16(gV1 + (k0 + 64),                &Vts[nxt][seg1 * 8]);
        }

        // ---- softmax numerator in registers (denominator from ROUNDED P)
        _Float16 hh[16];
        #pragma unroll
        for (int r = 0; r < 16; r++) {
            const float e = __expf(sacc[r] * 0.125f);
            hh[r] = (_Float16)e;
            lrow += (float)hh[r];
        }

        // ---- pack + key-half exchange -> PV A-fragments
        // reg r holds key (r&3)+8*(r>>2)+4*hf within the 32-key half.
        unsigned w01 = packh(hh[0],  hh[1]),  w23 = packh(hh[2],  hh[3]);
        unsigned w45 = packh(hh[4],  hh[5]),  w67 = packh(hh[6],  hh[7]);
        unsigned w89 = packh(hh[8],  hh[9]),  wab = packh(hh[10], hh[11]);
        unsigned wcd = packh(hh[12], hh[13]), wef = packh(hh[14], hh[15]);
        unsigned o01 = __shfl_xor((int)w01, 32), o23 = __shfl_xor((int)w23, 32);
        unsigned o45 = __shfl_xor((int)w45, 32), o67 = __shfl_xor((int)w67, 32);
        unsigned o89 = __shfl_xor((int)w89, 32), oab = __shfl_xor((int)wab, 32);
        unsigned ocd = __shfl_xor((int)wcd, 32), oef = __shfl_xor((int)wef, 32);
        // A-frag kk=0: keys 0..15 of half; kk=1: keys 16..31.
        f16x8 pa0 = mkfrag(hf ? o45 : w01, hf ? o67 : w23,
                           hf ? w45 : o01, hf ? w67 : o23);
        f16x8 pa1 = mkfrag(hf ? ocd : w89, hf ? oef : wab,
                           hf ? wcd : o89, hf ? wef : oab);

        // ---- O += P · V^T : O[32 q][32 d (dh)], contraction = 32 keys (kh).
        // B[k = key = kh*32 + kk*16 + hf*8 + j][col = d = dh*32+l31] from Vts.
        #pragma unroll
        for (int dh = 0; dh < 2; dh++) {
            const _Float16* vrow = VtsC + (dh * 32 + l31) * 64;
            f16x8 vf0 = *(const f16x8*)(vrow + (((kh * 4 + 0 + hf) ^ l7) * 8));
            f16x8 vf1 = *(const f16x8*)(vrow + (((kh * 4 + 2 + hf) ^ l7) * 8));
            Oacc[dh] = __builtin_amdgcn_mfma_f32_32x32x16_f16(pa0, vf0, Oacc[dh], 0, 0, 0);
            Oacc[dh] = __builtin_amdgcn_mfma_f32_32x32x16_f16(pa1, vf1, Oacc[dh], 0, 0, 0);
        }
    }

    // ---- epilogue: kh-pair reduce (O and denominator), then normalize+store.
    // Last tile staged nothing; __syncthreads below drains any residual state.
    float lsum = lrow + __shfl_xor(lrow, 32);   // full 32-key-half sum, q = l31
    __syncthreads();                            // all loop reads done; LDS reusable
    float* Obuf = (float*)&Ks[0][0];            // [64 q][64 d] f32 = 16 KB (all Ks)
    float* lbuf = (float*)&Vts[0][0];           // 64 f32
    if (kh) {
        #pragma unroll
        for (int dh = 0; dh < 2; dh++)
            #pragma unroll
            for (int r = 0; r < 16; r++) {
                const int q = (r & 3) + 8 * (r >> 2) + 4 * hf;
                Obuf[(qg * 32 + q) * 64 + dh * 32 + l31] = Oacc[dh][r];
            }
        if (lane < 32) lbuf[qg * 32 + lane] = lsum;
    }
    __syncthreads();
    if (!kh) {
        // lane (any half) holds denominator for q = l31; broadcast via shfl.
        const float dnrec = 1.f / (lsum + lbuf[qg * 32 + l31]);
        float dq[16];
        #pragma unroll
        for (int r = 0; r < 16; r++)
            dq[r] = __shfl(dnrec, (r & 3) + 8 * (r >> 2) + 4 * hf);
        #pragma unroll
        for (int dh = 0; dh < 2; dh++)
            #pragma unroll
            for (int r = 0; r < 16; r++) {
                const int q = (r & 3) + 8 * (r >> 2) + 4 * hf;
                const float v = (Oacc[dh][r] + Obuf[(qg * 32 + q) * 64 + dh * 32 + l31])
                                * dq[r];
                out[(size_t)(b * SEQ + q0 + qg * 32 + q) * DIMM + hd * HDIM + dh * 32 + l31] =
                    (_Float16)v;
            }
    }
}

// ---------------------------------------------------------------------------
extern "C" void kernel_launch(void* const* d_in, const int* in_sizes, int n_in,
                              void* d_out, int out_size, void* d_ws, size_t ws_size,
                              hipStream_t stream)
{
    const float* x    = (const float*)d_in[0];   // [2,2048,1024]
    const float* Wqkv = (const float*)d_in[1];   // [1024,3072]
    const float* bqkv = (const float*)d_in[2];   // [3072]
    const float* Wout = (const float*)d_in[3];   // [1024,1024]
    const float* bout = (const float*)d_in[4];   // [1024]
    float* out = (float*)d_out;                  // [2,2048,1024]

    _Float16* qkvh  = (_Float16*)d_ws;                   // 4096x3072
    _Float16* attnh = qkvh  + (size_t)ROWS * 3 * DIMM;   // 4096x1024
    _Float16* xh    = attnh + (size_t)ROWS * DIMM;       // 4096x1024
    _Float16* wqkvt = xh    + (size_t)ROWS * DIMM;       // 3072x1024
    _Float16* woutt = wqkvt + (size_t)3 * DIMM * DIMM;   // 1024x1024
    _Float16* vtg   = woutt + (size_t)DIMM * DIMM;       // 32 x 64 x 2048

    // 0) merged fp16 conversions (x, W_qkv^T, W_out^T)
    prep_kernel<<<3072, 256, 0, stream>>>(x, Wqkv, Wout, xh, wqkvt, woutt);
    // 1) qkv = x @ W_qkv + b_qkv   (fp16 out)
    {
        dim3 grid(3 * DIMM / 128, ROWS / 128);
        hgemm_bias_kernel<1><<<grid, 256, 0, stream>>>(xh, wqkvt, bqkv, qkvh, 3 * DIMM, DIMM);
    }
    // 1b) global V transpose
    {
        dim3 grid(SEQ / 64, BATCH * NHEADS);
        vtranspose_kernel<<<grid, 256, 0, stream>>>(qkvh, vtg);
    }
    // 2) attention -> attnh (fp16)
    {
        dim3 grid(SEQ / 64, BATCH * NHEADS);
        flash_attn_kernel<<<grid, 256, 0, stream>>>(qkvh, vtg, attnh);
    }
    // 3) out = attn @ W_out + b_out  (fp32 out)
    {
        dim3 grid(DIMM / 128, ROWS / 128);
        hgemm_bias_kernel<0><<<grid, 256, 0, stream>>>(attnh, woutt, bout, out, DIMM, DIMM);
    }
}

// Round 5
// 200.069 us; speedup vs baseline: 1.1483x; 1.0233x over previous
//
#include <hip/hip_runtime.h>
#include <math.h>

// Problem constants (AttentionLikeModel_75531294867774)
#define DIMM    1024
#define NHEADS  16
#define HDIM    64
#define BATCH   2
#define SEQ     2048
#define ROWS    (BATCH*SEQ)   // 4096

typedef _Float16 f16x8 __attribute__((ext_vector_type(8)));
typedef _Float16 f16x4 __attribute__((ext_vector_type(4)));
typedef float    f32x4 __attribute__((ext_vector_type(4)));
typedef float    f32x16 __attribute__((ext_vector_type(16)));

__device__ inline void gl_lds16(const void* g, void* l) {
    __builtin_amdgcn_global_load_lds(
        (const __attribute__((address_space(1))) void*)g,
        (__attribute__((address_space(3))) void*)l, 16, 0, 0);
}

static __device__ inline unsigned packh(_Float16 a, _Float16 b) {
    unsigned short ua = __builtin_bit_cast(unsigned short, a);
    unsigned short ub = __builtin_bit_cast(unsigned short, b);
    return (unsigned)ua | ((unsigned)ub << 16);
}
static __device__ inline f16x8 mkfrag(unsigned a, unsigned b, unsigned c, unsigned d) {
    union { unsigned u[4]; f16x8 v; } x;
    x.u[0] = a; x.u[1] = b; x.u[2] = c; x.u[3] = d;
    return x.v;
}

// ---------------------------------------------------------------------------
// Merged prep: blocks [0,2048) cvt x -> fp16; [2048,2816) W_qkv^T; [2816,3072) W_out^T
// ---------------------------------------------------------------------------
__device__ void tcvt64(const float* __restrict__ in, _Float16* __restrict__ out,
                       int K, int N, int k0, int n0, float (*tile)[65], int t)
{
    {
        const int c4 = (t & 15) * 4;
        const int r  = t >> 4;
        #pragma unroll
        for (int i = 0; i < 4; i++) {
            const int rr = r + 16 * i;
            float4 v = *(const float4*)(in + (size_t)(k0 + rr) * N + n0 + c4);
            tile[rr][c4] = v.x; tile[rr][c4 + 1] = v.y;
            tile[rr][c4 + 2] = v.z; tile[rr][c4 + 3] = v.w;
        }
    }
    __syncthreads();
    #pragma unroll
    for (int i = 0; i < 2; i++) {
        const int seg = t + 256 * i;
        const int n   = seg >> 3;
        const int kc  = (seg & 7) * 8;
        f16x8 o;
        #pragma unroll
        for (int j = 0; j < 8; j++) o[j] = (_Float16)tile[kc + j][n];
        *(f16x8*)(out + (size_t)(n0 + n) * K + k0 + kc) = o;
    }
}

__global__ __launch_bounds__(256)
void prep_kernel(const float* __restrict__ x, const float* __restrict__ Wqkv,
                 const float* __restrict__ Wout, _Float16* __restrict__ xh,
                 _Float16* __restrict__ wqkvt, _Float16* __restrict__ woutt)
{
    __shared__ float tile[64][65];
    const int bx = blockIdx.x;
    const int t  = threadIdx.x;
    if (bx < 2048) {                       // cvt x (4096x1024 / 8 / 256 = 2048 blocks)
        const int i = bx * 256 + t;
        const float4 a = *(const float4*)(x + (size_t)i * 8);
        const float4 b = *(const float4*)(x + (size_t)i * 8 + 4);
        f16x8 o;
        o[0] = (_Float16)a.x; o[1] = (_Float16)a.y; o[2] = (_Float16)a.z; o[3] = (_Float16)a.w;
        o[4] = (_Float16)b.x; o[5] = (_Float16)b.y; o[6] = (_Float16)b.z; o[7] = (_Float16)b.w;
        *(f16x8*)(xh + (size_t)i * 8) = o;
    } else if (bx < 2816) {                // W_qkv^T: grid (48,16)
        const int id = bx - 2048;
        const int gx = id % 48, gy = id / 48;
        tcvt64(Wqkv, wqkvt, DIMM, 3 * DIMM, gy * 64, gx * 64, tile, t);
    } else {                               // W_out^T: grid (16,16)
        const int id = bx - 2816;
        const int gx = id & 15, gy = id >> 4;
        tcvt64(Wout, woutt, DIMM, DIMM, gy * 64, gx * 64, tile, t);
    }
}

// ---------------------------------------------------------------------------
// V-transpose: qkvh V-third [b][key][h*64+d] -> vt[bh][d][key] (fp16)
// ---------------------------------------------------------------------------
__global__ __launch_bounds__(256)
void vtranspose_kernel(const _Float16* __restrict__ qkvh, _Float16* __restrict__ vt)
{
    __shared__ _Float16 tile[64][72];
    const int kt = blockIdx.x;
    const int bh = blockIdx.y;
    const int b  = bh >> 4, h = bh & 15;
    const int t  = threadIdx.x;
    {
        const int key = t >> 2, c4 = (t & 3) * 16;
        const _Float16* src = qkvh + ((size_t)(b * SEQ + kt * 64 + key)) * (3 * DIMM)
                              + 2 * DIMM + h * HDIM + c4;
        f16x8 v0 = *(const f16x8*)src;
        f16x8 v1 = *(const f16x8*)(src + 8);
        #pragma unroll
        for (int j = 0; j < 8; j++) {
            tile[c4 + j][key]     = v0[j];
            tile[c4 + 8 + j][key] = v1[j];
        }
    }
    __syncthreads();
    {
        const int d = t >> 2, k4 = (t & 3) * 16;
        f16x8 o0, o1;
        #pragma unroll
        for (int j = 0; j < 8; j++) { o0[j] = tile[d][k4 + j]; o1[j] = tile[d][k4 + 8 + j]; }
        _Float16* dst = vt + ((size_t)bh * 64 + d) * SEQ + kt * 64 + k4;
        *(f16x8*)dst       = o0;
        *(f16x8*)(dst + 8) = o1;
    }
}

// ---------------------------------------------------------------------------
// HGEMM + bias, dbuf pipelined (race-free-by-construction, proven pattern
// from the R4 flash kernel): per K-iter ONE __syncthreads; prefetch of tile
// t+1 issued immediately after the barrier (writes only buf[nxt]); fragment
// reads touch only buf[cur]. The barrier's implicit vmcnt(0) drains DMAs
// issued a FULL ITERATION earlier (latency already elapsed under the MFMAs)
// instead of just-issued loads -> removes the m97-structure per-iter drain.
// BM=128: 2x2 waves of 64x64 (qkv GEMM, LDS 64KB -> 2 blk/CU).
// BM=64:  2x2 waves of 32x64 (out GEMM, grid 512 = 2 blk/CU vs 1 before).
// ---------------------------------------------------------------------------
template<int OUT_F16, int BM>
__global__ __launch_bounds__(256)
void hgemm_db_kernel(const _Float16* __restrict__ A, const _Float16* __restrict__ Bt,
                     const float* __restrict__ bias, void* __restrict__ Cout,
                     int N, int K)
{
    constexpr int MI = BM / 32;          // row frag-blocks per wave == A segs/thread
    __shared__ _Float16 As[2][BM * 64];
    __shared__ _Float16 Bs[2][128 * 64];

    const int t    = threadIdx.x;
    const int w    = t >> 6, lane = t & 63;
    const int quad = lane >> 4, l16 = lane & 15;
    const int wr   = w >> 1, wc = w & 1;
    const int row0 = blockIdx.y * BM, col0 = blockIdx.x * 128;
    const int sw   = l16 & 7;

    f32x4 acc[MI][4];
    #pragma unroll
    for (int i = 0; i < MI; i++)
        #pragma unroll
        for (int j = 0; j < 4; j++)
            #pragma unroll
            for (int r = 0; r < 4; r++) acc[i][j][r] = 0.f;

    // staging descriptors: A = MI 16B segs/thread, B = 4 segs/thread
    const _Float16* gA[MI];
    int aofs[MI];
    #pragma unroll
    for (int j = 0; j < MI; j++) {
        const int s   = t + 256 * j;
        const int row = s >> 3;
        const int kb  = (s & 7) ^ (row & 7);
        gA[j] = A + (size_t)(row0 + row) * K + kb * 8;
        aofs[j] = s * 8;
    }
    const _Float16* gB[4];
    int bofs[4];
    #pragma unroll
    for (int j = 0; j < 4; j++) {
        const int s   = t + 256 * j;
        const int row = s >> 3;
        const int kb  = (s & 7) ^ (row & 7);
        gB[j] = Bt + (size_t)(col0 + row) * K + kb * 8;
        bofs[j] = s * 8;
    }

    // prologue: stage tile 0 into buffer 0; pointers advance to tile 1
    #pragma unroll
    for (int j = 0; j < MI; j++) gl_lds16(gA[j], &As[0][aofs[j]]);
    #pragma unroll
    for (int j = 0; j < 4; j++)  gl_lds16(gB[j], &Bs[0][bofs[j]]);
    #pragma unroll
    for (int j = 0; j < MI; j++) gA[j] += 64;
    #pragma unroll
    for (int j = 0; j < 4; j++)  gB[j] += 64;

    const int niter = K >> 6;
    #pragma unroll 1
    for (int it = 0; it < niter; it++) {
        const int cur = it & 1;
        // ONE barrier: drains buf[cur] DMAs (issued last iter) and joins all
        // waves' reads of buf[cur^1] (last iter) before we overwrite it.
        __syncthreads();

        if (it + 1 < niter) {
            const int nxt = cur ^ 1;
            #pragma unroll
            for (int j = 0; j < MI; j++) gl_lds16(gA[j], &As[nxt][aofs[j]]);
            #pragma unroll
            for (int j = 0; j < 4; j++)  gl_lds16(gB[j], &Bs[nxt][bofs[j]]);
            #pragma unroll
            for (int j = 0; j < MI; j++) gA[j] += 64;
            #pragma unroll
            for (int j = 0; j < 4; j++)  gB[j] += 64;
        }

        const _Float16* AsC = &As[cur][0];
        const _Float16* BsC = &Bs[cur][0];
        f16x8 af[MI][2], bf[4][2];
        #pragma unroll
        for (int i = 0; i < MI; i++) {
            const int arow = wr * (BM / 2) + i * 16 + l16;
            #pragma unroll
            for (int hh = 0; hh < 2; hh++)
                af[i][hh] = *(const f16x8*)(AsC + (arow * 8 + ((hh * 4 + quad) ^ sw)) * 8);
        }
        #pragma unroll
        for (int j = 0; j < 4; j++) {
            const int brow = wc * 64 + j * 16 + l16;
            #pragma unroll
            for (int hh = 0; hh < 2; hh++)
                bf[j][hh] = *(const f16x8*)(BsC + (brow * 8 + ((hh * 4 + quad) ^ sw)) * 8);
        }
        #pragma unroll
        for (int i = 0; i < MI; i++)
            #pragma unroll
            for (int j = 0; j < 4; j++) {
                acc[i][j] = __builtin_amdgcn_mfma_f32_16x16x32_f16(af[i][0], bf[j][0], acc[i][j], 0, 0, 0);
                acc[i][j] = __builtin_amdgcn_mfma_f32_16x16x32_f16(af[i][1], bf[j][1], acc[i][j], 0, 0, 0);
            }
    }

    #pragma unroll
    for (int j = 0; j < 4; j++) {
        const int col = col0 + wc * 64 + j * 16 + l16;
        const float bv = bias[col];
        #pragma unroll
        for (int i = 0; i < MI; i++) {
            const int row = row0 + wr * (BM / 2) + i * 16 + quad * 4;
            #pragma unroll
            for (int r = 0; r < 4; r++) {
                const float v = acc[i][j][r] + bv;
                if (OUT_F16)
                    ((_Float16*)Cout)[(size_t)(row + r) * N + col] = (_Float16)v;
                else
                    ((float*)Cout)[(size_t)(row + r) * N + col] = v;
            }
        }
    }
}

// ---------------------------------------------------------------------------
// MFMA flash attention — in-register P (32x32x16 MFMA), race-free-by-
// construction sync (ONE __syncthreads per tile; prefetch writes only
// buf[nxt], reads only buf[cur]). UNCHANGED from round 4 (verified, 65 µs,
// absmax 4.88e-4).
// ---------------------------------------------------------------------------
__global__ __launch_bounds__(256, 4)
void flash_attn_kernel(const _Float16* __restrict__ qkv,
                       const _Float16* __restrict__ vtg,
                       _Float16* __restrict__ out)
{
    const int qt = blockIdx.x;          // 0..31
    const int bh = blockIdx.y;          // 0..31
    const int b  = bh >> 4, hd = bh & 15;
    const int t    = threadIdx.x;
    const int w    = t >> 6;
    const int lane = t & 63;
    const int qg   = w >> 1;            // q-group (32 rows)
    const int kh   = w & 1;             // key-half (32 keys)
    const int l31  = lane & 31;
    const int hf   = lane >> 5;         // lane half
    const int l7   = lane & 7;

    __shared__ __align__(16) _Float16 Ks [2][64 * 64];
    __shared__ __align__(16) _Float16 Vts[2][64 * 64];

    const int q0 = qt * 64;
    const size_t rstr = 3 * DIMM;
    const _Float16* qbase = qkv + (size_t)b * SEQ * rstr;

    // ---- Q B-fragments (register-resident, unscaled; 0.125 applied on f32 scores)
    f16x8 qf[4];
    {
        const _Float16* qrow = qbase + (size_t)(q0 + qg * 32 + l31) * rstr + hd * HDIM;
        #pragma unroll
        for (int dd = 0; dd < 4; dd++)
            qf[dd] = *(const f16x8*)(qrow + dd * 16 + hf * 8);
    }

    f32x16 Oacc[2];
    #pragma unroll
    for (int dh = 0; dh < 2; dh++)
        #pragma unroll
        for (int r = 0; r < 16; r++) Oacc[dh][r] = 0.f;
    float lrow = 0.f;

    // staging descriptors (two 16B segments each for K and Vt per thread)
    const int seg0 = t, seg1 = t + 256;
    const int r0 = seg0 >> 3, lb0 = (seg0 & 7) ^ (r0 & 7);
    const int r1 = seg1 >> 3, lb1 = (seg1 & 7) ^ (r1 & 7);
    const _Float16* gK0 = qbase + (size_t)r0 * rstr + DIMM + hd * HDIM + lb0 * 8;
    const _Float16* gK1 = qbase + (size_t)r1 * rstr + DIMM + hd * HDIM + lb1 * 8;
    const _Float16* gV0 = vtg + ((size_t)bh * 64 + r0) * SEQ + lb0 * 8;
    const _Float16* gV1 = vtg + ((size_t)bh * 64 + r1) * SEQ + lb1 * 8;

    // ---- prologue: stage tile 0 into buffer 0
    gl_lds16(gK0, &Ks [0][seg0 * 8]);
    gl_lds16(gK1, &Ks [0][seg1 * 8]);
    gl_lds16(gV0, &Vts[0][seg0 * 8]);
    gl_lds16(gV1, &Vts[0][seg1 * 8]);

    #pragma unroll 2
    for (int k0 = 0; k0 < SEQ; k0 += 64) {
        const int cur = (k0 >> 6) & 1;
        const _Float16* KsC  = &Ks [cur][0];
        const _Float16* VtsC = &Vts[cur][0];

        __syncthreads();

        // ---- QK^T: S^T[32 keys (kh)][32 q (qg)], K-dim = 64 d in 4 slices.
        f32x16 sacc;
        #pragma unroll
        for (int r = 0; r < 16; r++) sacc[r] = 0.f;
        #pragma unroll
        for (int dd = 0; dd < 4; dd++) {
            f16x8 kf = *(const f16x8*)(KsC + (kh * 32 + l31) * 64 + (((dd * 2 + hf) ^ l7) * 8));
            sacc = __builtin_amdgcn_mfma_f32_32x32x16_f16(kf, qf[dd], sacc, 0, 0, 0);
        }

        // ---- prefetch next tile into buf[nxt]
        if (k0 + 64 < SEQ) {
            const int nxt = cur ^ 1;
            gl_lds16(gK0 + (size_t)(k0 + 64) * rstr, &Ks [nxt][seg0 * 8]);
            gl_lds16(gK1 + (size_t)(k0 + 64) * rstr, &Ks [nxt][seg1 * 8]);
            gl_lds16(gV0 + (k0 + 64),                &Vts[nxt][seg0 * 8]);
            gl_lds16(gV1 + (k0 + 64),                &Vts[nxt][seg1 * 8]);
        }

        // ---- softmax numerator in registers (denominator from ROUNDED P)
        _Float16 hh[16];
        #pragma unroll
        for (int r = 0; r < 16; r++) {
            const float e = __expf(sacc[r] * 0.125f);
            hh[r] = (_Float16)e;
            lrow += (float)hh[r];
        }

        // ---- pack + key-half exchange -> PV A-fragments
        unsigned w01 = packh(hh[0],  hh[1]),  w23 = packh(hh[2],  hh[3]);
        unsigned w45 = packh(hh[4],  hh[5]),  w67 = packh(hh[6],  hh[7]);
        unsigned w89 = packh(hh[8],  hh[9]),  wab = packh(hh[10], hh[11]);
        unsigned wcd = packh(hh[12], hh[13]), wef = packh(hh[14], hh[15]);
        unsigned o01 = __shfl_xor((int)w01, 32), o23 = __shfl_xor((int)w23, 32);
        unsigned o45 = __shfl_xor((int)w45, 32), o67 = __shfl_xor((int)w67, 32);
        unsigned o89 = __shfl_xor((int)w89, 32), oab = __shfl_xor((int)wab, 32);
        unsigned ocd = __shfl_xor((int)wcd, 32), oef = __shfl_xor((int)wef, 32);
        f16x8 pa0 = mkfrag(hf ? o45 : w01, hf ? o67 : w23,
                           hf ? w45 : o01, hf ? w67 : o23);
        f16x8 pa1 = mkfrag(hf ? ocd : w89, hf ? oef : wab,
                           hf ? wcd : o89, hf ? wef : oab);

        // ---- O += P · V^T
        #pragma unroll
        for (int dh = 0; dh < 2; dh++) {
            const _Float16* vrow = VtsC + (dh * 32 + l31) * 64;
            f16x8 vf0 = *(const f16x8*)(vrow + (((kh * 4 + 0 + hf) ^ l7) * 8));
            f16x8 vf1 = *(const f16x8*)(vrow + (((kh * 4 + 2 + hf) ^ l7) * 8));
            Oacc[dh] = __builtin_amdgcn_mfma_f32_32x32x16_f16(pa0, vf0, Oacc[dh], 0, 0, 0);
            Oacc[dh] = __builtin_amdgcn_mfma_f32_32x32x16_f16(pa1, vf1, Oacc[dh], 0, 0, 0);
        }
    }

    // ---- epilogue: kh-pair reduce (O and denominator), then normalize+store.
    float lsum = lrow + __shfl_xor(lrow, 32);
    __syncthreads();
    float* Obuf = (float*)&Ks[0][0];
    float* lbuf = (float*)&Vts[0][0];
    if (kh) {
        #pragma unroll
        for (int dh = 0; dh < 2; dh++)
            #pragma unroll
            for (int r = 0; r < 16; r++) {
                const int q = (r & 3) + 8 * (r >> 2) + 4 * hf;
                Obuf[(qg * 32 + q) * 64 + dh * 32 + l31] = Oacc[dh][r];
            }
        if (lane < 32) lbuf[qg * 32 + lane] = lsum;
    }
    __syncthreads();
    if (!kh) {
        const float dnrec = 1.f / (lsum + lbuf[qg * 32 + l31]);
        float dq[16];
        #pragma unroll
        for (int r = 0; r < 16; r++)
            dq[r] = __shfl(dnrec, (r & 3) + 8 * (r >> 2) + 4 * hf);
        #pragma unroll
        for (int dh = 0; dh < 2; dh++)
            #pragma unroll
            for (int r = 0; r < 16; r++) {
                const int q = (r & 3) + 8 * (r >> 2) + 4 * hf;
                const float v = (Oacc[dh][r] + Obuf[(qg * 32 + q) * 64 + dh * 32 + l31])
                                * dq[r];
                out[(size_t)(b * SEQ + q0 + qg * 32 + q) * DIMM + hd * HDIM + dh * 32 + l31] =
                    (_Float16)v;
            }
    }
}

// ---------------------------------------------------------------------------
extern "C" void kernel_launch(void* const* d_in, const int* in_sizes, int n_in,
                              void* d_out, int out_size, void* d_ws, size_t ws_size,
                              hipStream_t stream)
{
    const float* x    = (const float*)d_in[0];   // [2,2048,1024]
    const float* Wqkv = (const float*)d_in[1];   // [1024,3072]
    const float* bqkv = (const float*)d_in[2];   // [3072]
    const float* Wout = (const float*)d_in[3];   // [1024,1024]
    const float* bout = (const float*)d_in[4];   // [1024]
    float* out = (float*)d_out;                  // [2,2048,1024]

    _Float16* qkvh  = (_Float16*)d_ws;                   // 4096x3072
    _Float16* attnh = qkvh  + (size_t)ROWS * 3 * DIMM;   // 4096x1024
    _Float16* xh    = attnh + (size_t)ROWS * DIMM;       // 4096x1024
    _Float16* wqkvt = xh    + (size_t)ROWS * DIMM;       // 3072x1024
    _Float16* woutt = wqkvt + (size_t)3 * DIMM * DIMM;   // 1024x1024
    _Float16* vtg   = woutt + (size_t)DIMM * DIMM;       // 32 x 64 x 2048

    // 0) merged fp16 conversions (x, W_qkv^T, W_out^T)
    prep_kernel<<<3072, 256, 0, stream>>>(x, Wqkv, Wout, xh, wqkvt, woutt);
    // 1) qkv = x @ W_qkv + b_qkv   (fp16 out) — 128x128 dbuf-pipelined
    {
        dim3 grid(3 * DIMM / 128, ROWS / 128);
        hgemm_db_kernel<1, 128><<<grid, 256, 0, stream>>>(xh, wqkvt, bqkv, qkvh, 3 * DIMM, DIMM);
    }
    // 1b) global V transpose
    {
        dim3 grid(SEQ / 64, BATCH * NHEADS);
        vtranspose_kernel<<<grid, 256, 0, stream>>>(qkvh, vtg);
    }
    // 2) attention -> attnh (fp16)
    {
        dim3 grid(SEQ / 64, BATCH * NHEADS);
        flash_attn_kernel<<<grid, 256, 0, stream>>>(qkvh, vtg, attnh);
    }
    // 3) out = attn @ W_out + b_out  (fp32 out) — 64x128 dbuf-pipelined, 512 blocks
    {
        dim3 grid(DIMM / 128, ROWS / 64);
        hgemm_db_kernel<0, 64><<<grid, 256, 0, stream>>>(attnh, woutt, bout, out, DIMM, DIMM);
    }
}

// Round 6
// 190.600 us; speedup vs baseline: 1.2053x; 1.0497x over previous
//
#include <hip/hip_runtime.h>
#include <math.h>

// Problem constants (AttentionLikeModel_75531294867774)
#define DIMM    1024
#define NHEADS  16
#define HDIM    64
#define BATCH   2
#define SEQ     2048
#define ROWS    (BATCH*SEQ)   // 4096

typedef _Float16 f16x8 __attribute__((ext_vector_type(8)));
typedef _Float16 f16x4 __attribute__((ext_vector_type(4)));
typedef _Float16 f16x2 __attribute__((ext_vector_type(2)));
typedef float    f32x4 __attribute__((ext_vector_type(4)));
typedef float    f32x16 __attribute__((ext_vector_type(16)));

__device__ inline void gl_lds16(const void* g, void* l) {
    __builtin_amdgcn_global_load_lds(
        (const __attribute__((address_space(1))) void*)g,
        (__attribute__((address_space(3))) void*)l, 16, 0, 0);
}

static __device__ inline f16x8 mkfrag(unsigned a, unsigned b, unsigned c, unsigned d) {
    union { unsigned u[4]; f16x8 v; } x;
    x.u[0] = a; x.u[1] = b; x.u[2] = c; x.u[3] = d;
    return x.v;
}

// ---------------------------------------------------------------------------
// Merged prep: blocks [0,2048) cvt x -> fp16; [2048,2816) W_qkv^T; [2816,3072) W_out^T
// ---------------------------------------------------------------------------
__device__ void tcvt64(const float* __restrict__ in, _Float16* __restrict__ out,
                       int K, int N, int k0, int n0, float (*tile)[65], int t)
{
    {
        const int c4 = (t & 15) * 4;
        const int r  = t >> 4;
        #pragma unroll
        for (int i = 0; i < 4; i++) {
            const int rr = r + 16 * i;
            float4 v = *(const float4*)(in + (size_t)(k0 + rr) * N + n0 + c4);
            tile[rr][c4] = v.x; tile[rr][c4 + 1] = v.y;
            tile[rr][c4 + 2] = v.z; tile[rr][c4 + 3] = v.w;
        }
    }
    __syncthreads();
    #pragma unroll
    for (int i = 0; i < 2; i++) {
        const int seg = t + 256 * i;
        const int n   = seg >> 3;
        const int kc  = (seg & 7) * 8;
        f16x8 o;
        #pragma unroll
        for (int j = 0; j < 8; j++) o[j] = (_Float16)tile[kc + j][n];
        *(f16x8*)(out + (size_t)(n0 + n) * K + k0 + kc) = o;
    }
}

__global__ __launch_bounds__(256)
void prep_kernel(const float* __restrict__ x, const float* __restrict__ Wqkv,
                 const float* __restrict__ Wout, _Float16* __restrict__ xh,
                 _Float16* __restrict__ wqkvt, _Float16* __restrict__ woutt)
{
    __shared__ float tile[64][65];
    const int bx = blockIdx.x;
    const int t  = threadIdx.x;
    if (bx < 2048) {                       // cvt x (4096x1024 / 8 / 256 = 2048 blocks)
        const int i = bx * 256 + t;
        const float4 a = *(const float4*)(x + (size_t)i * 8);
        const float4 b = *(const float4*)(x + (size_t)i * 8 + 4);
        f16x8 o;
        o[0] = (_Float16)a.x; o[1] = (_Float16)a.y; o[2] = (_Float16)a.z; o[3] = (_Float16)a.w;
        o[4] = (_Float16)b.x; o[5] = (_Float16)b.y; o[6] = (_Float16)b.z; o[7] = (_Float16)b.w;
        *(f16x8*)(xh + (size_t)i * 8) = o;
    } else if (bx < 2816) {                // W_qkv^T: grid (48,16)
        const int id = bx - 2048;
        const int gx = id % 48, gy = id / 48;
        tcvt64(Wqkv, wqkvt, DIMM, 3 * DIMM, gy * 64, gx * 64, tile, t);
    } else {                               // W_out^T: grid (16,16)
        const int id = bx - 2816;
        const int gx = id & 15, gy = id >> 4;
        tcvt64(Wout, woutt, DIMM, DIMM, gy * 64, gx * 64, tile, t);
    }
}

// ---------------------------------------------------------------------------
// HGEMM + bias, dbuf pipelined (one __syncthreads per K-iter; prefetch writes
// only buf[nxt], fragment reads only buf[cur]).
// FUSEVT=1 (qkv GEMM): blocks with col0 >= 2048 compute the V-third and write
// it TRANSPOSED directly to vtg[bh][d][key] (f16x4 = 4 consecutive keys per
// thread; per wave 128B contiguous per column -> cache-line-complete writes).
// This replaces the standalone vtranspose kernel. V-third of qkvh is never
// written (nothing reads it).
// ---------------------------------------------------------------------------
template<int OUT_F16, int BM, int FUSEVT>
__global__ __launch_bounds__(256)
void hgemm_db_kernel(const _Float16* __restrict__ A, const _Float16* __restrict__ Bt,
                     const float* __restrict__ bias, void* __restrict__ Cout,
                     _Float16* __restrict__ vtg, int N, int K)
{
    constexpr int MI = BM / 32;          // row frag-blocks per wave == A segs/thread
    __shared__ _Float16 As[2][BM * 64];
    __shared__ _Float16 Bs[2][128 * 64];

    const int t    = threadIdx.x;
    const int w    = t >> 6, lane = t & 63;
    const int quad = lane >> 4, l16 = lane & 15;
    const int wr   = w >> 1, wc = w & 1;
    const int row0 = blockIdx.y * BM, col0 = blockIdx.x * 128;
    const int sw   = l16 & 7;

    f32x4 acc[MI][4];
    #pragma unroll
    for (int i = 0; i < MI; i++)
        #pragma unroll
        for (int j = 0; j < 4; j++)
            #pragma unroll
            for (int r = 0; r < 4; r++) acc[i][j][r] = 0.f;

    // staging descriptors: A = MI 16B segs/thread, B = 4 segs/thread
    const _Float16* gA[MI];
    int aofs[MI];
    #pragma unroll
    for (int j = 0; j < MI; j++) {
        const int s   = t + 256 * j;
        const int row = s >> 3;
        const int kb  = (s & 7) ^ (row & 7);
        gA[j] = A + (size_t)(row0 + row) * K + kb * 8;
        aofs[j] = s * 8;
    }
    const _Float16* gB[4];
    int bofs[4];
    #pragma unroll
    for (int j = 0; j < 4; j++) {
        const int s   = t + 256 * j;
        const int row = s >> 3;
        const int kb  = (s & 7) ^ (row & 7);
        gB[j] = Bt + (size_t)(col0 + row) * K + kb * 8;
        bofs[j] = s * 8;
    }

    // prologue: stage tile 0 into buffer 0; pointers advance to tile 1
    #pragma unroll
    for (int j = 0; j < MI; j++) gl_lds16(gA[j], &As[0][aofs[j]]);
    #pragma unroll
    for (int j = 0; j < 4; j++)  gl_lds16(gB[j], &Bs[0][bofs[j]]);
    #pragma unroll
    for (int j = 0; j < MI; j++) gA[j] += 64;
    #pragma unroll
    for (int j = 0; j < 4; j++)  gB[j] += 64;

    const int niter = K >> 6;
    #pragma unroll 1
    for (int it = 0; it < niter; it++) {
        const int cur = it & 1;
        __syncthreads();

        if (it + 1 < niter) {
            const int nxt = cur ^ 1;
            #pragma unroll
            for (int j = 0; j < MI; j++) gl_lds16(gA[j], &As[nxt][aofs[j]]);
            #pragma unroll
            for (int j = 0; j < 4; j++)  gl_lds16(gB[j], &Bs[nxt][bofs[j]]);
            #pragma unroll
            for (int j = 0; j < MI; j++) gA[j] += 64;
            #pragma unroll
            for (int j = 0; j < 4; j++)  gB[j] += 64;
        }

        const _Float16* AsC = &As[cur][0];
        const _Float16* BsC = &Bs[cur][0];
        f16x8 af[MI][2], bf[4][2];
        #pragma unroll
        for (int i = 0; i < MI; i++) {
            const int arow = wr * (BM / 2) + i * 16 + l16;
            #pragma unroll
            for (int hh = 0; hh < 2; hh++)
                af[i][hh] = *(const f16x8*)(AsC + (arow * 8 + ((hh * 4 + quad) ^ sw)) * 8);
        }
        #pragma unroll
        for (int j = 0; j < 4; j++) {
            const int brow = wc * 64 + j * 16 + l16;
            #pragma unroll
            for (int hh = 0; hh < 2; hh++)
                bf[j][hh] = *(const f16x8*)(BsC + (brow * 8 + ((hh * 4 + quad) ^ sw)) * 8);
        }
        #pragma unroll
        for (int i = 0; i < MI; i++)
            #pragma unroll
            for (int j = 0; j < 4; j++) {
                acc[i][j] = __builtin_amdgcn_mfma_f32_16x16x32_f16(af[i][0], bf[j][0], acc[i][j], 0, 0, 0);
                acc[i][j] = __builtin_amdgcn_mfma_f32_16x16x32_f16(af[i][1], bf[j][1], acc[i][j], 0, 0, 0);
            }
    }

    if (FUSEVT && blockIdx.x >= 16) {
        // V-third: write transposed to vtg[bh][d][key]
        #pragma unroll
        for (int j = 0; j < 4; j++) {
            const int col = col0 + wc * 64 + j * 16 + l16;   // 2048..3071
            const float bv = bias[col];
            const int hv = (col - 2048) >> 6;                // head
            const int dv = col & 63;                         // head-dim
            #pragma unroll
            for (int i = 0; i < MI; i++) {
                const int row = row0 + wr * (BM / 2) + i * 16 + quad * 4;
                const int bb  = row >> 11;                   // batch
                const int key = row & 2047;
                f16x4 o;
                #pragma unroll
                for (int r = 0; r < 4; r++) o[r] = (_Float16)(acc[i][j][r] + bv);
                *(f16x4*)(vtg + ((size_t)(bb * 16 + hv) * 64 + dv) * SEQ + key) = o;
            }
        }
        return;
    }

    #pragma unroll
    for (int j = 0; j < 4; j++) {
        const int col = col0 + wc * 64 + j * 16 + l16;
        const float bv = bias[col];
        #pragma unroll
        for (int i = 0; i < MI; i++) {
            const int row = row0 + wr * (BM / 2) + i * 16 + quad * 4;
            #pragma unroll
            for (int r = 0; r < 4; r++) {
                const float v = acc[i][j][r] + bv;
                if (OUT_F16)
                    ((_Float16*)Cout)[(size_t)(row + r) * N + col] = (_Float16)v;
                else
                    ((float*)Cout)[(size_t)(row + r) * N + col] = v;
            }
        }
    }
}

// ---------------------------------------------------------------------------
// MFMA flash attention — in-register P (32x32x16 MFMA), race-free-by-
// construction sync (ONE __syncthreads per tile). This round: T12 exchange —
// cvt_pkrtz packs 2 f32->f16x2 in one op (8 vs 16cvt+8pack) and
// v_permlane32_swap_b32 (VALU) replaces 8 ds_bpermute-shfl + 16 cndmask:
// swap(a,b) -> newa = {a for lanes<32 | b[partner] for lanes>=32} = word_k,
//              newb = {a[partner] | b} = word_{k+2}. 4 swaps build both PV
// A-fragments. Denominator = unrounded f32 sum (R0-proven numerics).
// ---------------------------------------------------------------------------
__global__ __launch_bounds__(256, 4)
void flash_attn_kernel(const _Float16* __restrict__ qkv,
                       const _Float16* __restrict__ vtg,
                       _Float16* __restrict__ out)
{
    const int qt = blockIdx.x;          // 0..31
    const int bh = blockIdx.y;          // 0..31
    const int b  = bh >> 4, hd = bh & 15;
    const int t    = threadIdx.x;
    const int w    = t >> 6;
    const int lane = t & 63;
    const int qg   = w >> 1;            // q-group (32 rows)
    const int kh   = w & 1;             // key-half (32 keys)
    const int l31  = lane & 31;
    const int hf   = lane >> 5;         // lane half
    const int l7   = lane & 7;

    __shared__ __align__(16) _Float16 Ks [2][64 * 64];
    __shared__ __align__(16) _Float16 Vts[2][64 * 64];

    const int q0 = qt * 64;
    const size_t rstr = 3 * DIMM;
    const _Float16* qbase = qkv + (size_t)b * SEQ * rstr;

    // ---- Q B-fragments (register-resident, unscaled; 0.125 applied on f32 scores)
    f16x8 qf[4];
    {
        const _Float16* qrow = qbase + (size_t)(q0 + qg * 32 + l31) * rstr + hd * HDIM;
        #pragma unroll
        for (int dd = 0; dd < 4; dd++)
            qf[dd] = *(const f16x8*)(qrow + dd * 16 + hf * 8);
    }

    f32x16 Oacc[2];
    #pragma unroll
    for (int dh = 0; dh < 2; dh++)
        #pragma unroll
        for (int r = 0; r < 16; r++) Oacc[dh][r] = 0.f;
    float lrow = 0.f;

    // staging descriptors (two 16B segments each for K and Vt per thread)
    const int seg0 = t, seg1 = t + 256;
    const int r0 = seg0 >> 3, lb0 = (seg0 & 7) ^ (r0 & 7);
    const int r1 = seg1 >> 3, lb1 = (seg1 & 7) ^ (r1 & 7);
    const _Float16* gK0 = qbase + (size_t)r0 * rstr + DIMM + hd * HDIM + lb0 * 8;
    const _Float16* gK1 = qbase + (size_t)r1 * rstr + DIMM + hd * HDIM + lb1 * 8;
    const _Float16* gV0 = vtg + ((size_t)bh * 64 + r0) * SEQ + lb0 * 8;
    const _Float16* gV1 = vtg + ((size_t)bh * 64 + r1) * SEQ + lb1 * 8;

    // ---- prologue: stage tile 0 into buffer 0
    gl_lds16(gK0, &Ks [0][seg0 * 8]);
    gl_lds16(gK1, &Ks [0][seg1 * 8]);
    gl_lds16(gV0, &Vts[0][seg0 * 8]);
    gl_lds16(gV1, &Vts[0][seg1 * 8]);

    #pragma unroll 2
    for (int k0 = 0; k0 < SEQ; k0 += 64) {
        const int cur = (k0 >> 6) & 1;
        const _Float16* KsC  = &Ks [cur][0];
        const _Float16* VtsC = &Vts[cur][0];

        __syncthreads();

        // ---- QK^T: S^T[32 keys (kh)][32 q (qg)], K-dim = 64 d in 4 slices.
        f32x16 sacc;
        #pragma unroll
        for (int r = 0; r < 16; r++) sacc[r] = 0.f;
        #pragma unroll
        for (int dd = 0; dd < 4; dd++) {
            f16x8 kf = *(const f16x8*)(KsC + (kh * 32 + l31) * 64 + (((dd * 2 + hf) ^ l7) * 8));
            sacc = __builtin_amdgcn_mfma_f32_32x32x16_f16(kf, qf[dd], sacc, 0, 0, 0);
        }

        // ---- prefetch next tile into buf[nxt]
        if (k0 + 64 < SEQ) {
            const int nxt = cur ^ 1;
            gl_lds16(gK0 + (size_t)(k0 + 64) * rstr, &Ks [nxt][seg0 * 8]);
            gl_lds16(gK1 + (size_t)(k0 + 64) * rstr, &Ks [nxt][seg1 * 8]);
            gl_lds16(gV0 + (k0 + 64),                &Vts[nxt][seg0 * 8]);
            gl_lds16(gV1 + (k0 + 64),                &Vts[nxt][seg1 * 8]);
        }

        // ---- softmax numerator (f32; denominator = unrounded sum, R0-proven)
        float e[16];
        #pragma unroll
        for (int r = 0; r < 16; r++) {
            e[r] = __expf(sacc[r] * 0.125f);
            lrow += e[r];
        }

        // ---- pack (cvt_pkrtz) + key-half exchange (permlane32_swap, VALU)
        unsigned w01 = __builtin_bit_cast(unsigned, __builtin_amdgcn_cvt_pkrtz(e[0],  e[1]));
        unsigned w23 = __builtin_bit_cast(unsigned, __builtin_amdgcn_cvt_pkrtz(e[2],  e[3]));
        unsigned w45 = __builtin_bit_cast(unsigned, __builtin_amdgcn_cvt_pkrtz(e[4],  e[5]));
        unsigned w67 = __builtin_bit_cast(unsigned, __builtin_amdgcn_cvt_pkrtz(e[6],  e[7]));
        unsigned w89 = __builtin_bit_cast(unsigned, __builtin_amdgcn_cvt_pkrtz(e[8],  e[9]));
        unsigned wab = __builtin_bit_cast(unsigned, __builtin_amdgcn_cvt_pkrtz(e[10], e[11]));
        unsigned wcd = __builtin_bit_cast(unsigned, __builtin_amdgcn_cvt_pkrtz(e[12], e[13]));
        unsigned wef = __builtin_bit_cast(unsigned, __builtin_amdgcn_cvt_pkrtz(e[14], e[15]));
        // swap(a,b): a.hi-half <-> b.lo-half  =>  a' = word_k, b' = word_{k+2}
        unsigned p00 = w01, p02 = w45;
        asm("v_permlane32_swap_b32 %0, %1" : "+v"(p00), "+v"(p02));
        unsigned p01 = w23, p03 = w67;
        asm("v_permlane32_swap_b32 %0, %1" : "+v"(p01), "+v"(p03));
        unsigned p10 = w89, p12 = wcd;
        asm("v_permlane32_swap_b32 %0, %1" : "+v"(p10), "+v"(p12));
        unsigned p11 = wab, p13 = wef;
        asm("v_permlane32_swap_b32 %0, %1" : "+v"(p11), "+v"(p13));
        f16x8 pa0 = mkfrag(p00, p01, p02, p03);
        f16x8 pa1 = mkfrag(p10, p11, p12, p13);

        // ---- O += P · V^T
        #pragma unroll
        for (int dh = 0; dh < 2; dh++) {
            const _Float16* vrow = VtsC + (dh * 32 + l31) * 64;
            f16x8 vf0 = *(const f16x8*)(vrow + (((kh * 4 + 0 + hf) ^ l7) * 8));
            f16x8 vf1 = *(const f16x8*)(vrow + (((kh * 4 + 2 + hf) ^ l7) * 8));
            Oacc[dh] = __builtin_amdgcn_mfma_f32_32x32x16_f16(pa0, vf0, Oacc[dh], 0, 0, 0);
            Oacc[dh] = __builtin_amdgcn_mfma_f32_32x32x16_f16(pa1, vf1, Oacc[dh], 0, 0, 0);
        }
    }

    // ---- epilogue: kh-pair reduce (O and denominator), then normalize+store.
    float lsum = lrow + __shfl_xor(lrow, 32);
    __syncthreads();
    float* Obuf = (float*)&Ks[0][0];
    float* lbuf = (float*)&Vts[0][0];
    if (kh) {
        #pragma unroll
        for (int dh = 0; dh < 2; dh++)
            #pragma unroll
            for (int r = 0; r < 16; r++) {
                const int q = (r & 3) + 8 * (r >> 2) + 4 * hf;
                Obuf[(qg * 32 + q) * 64 + dh * 32 + l31] = Oacc[dh][r];
            }
        if (lane < 32) lbuf[qg * 32 + lane] = lsum;
    }
    __syncthreads();
    if (!kh) {
        const float dnrec = 1.f / (lsum + lbuf[qg * 32 + l31]);
        float dq[16];
        #pragma unroll
        for (int r = 0; r < 16; r++)
            dq[r] = __shfl(dnrec, (r & 3) + 8 * (r >> 2) + 4 * hf);
        #pragma unroll
        for (int dh = 0; dh < 2; dh++)
            #pragma unroll
            for (int r = 0; r < 16; r++) {
                const int q = (r & 3) + 8 * (r >> 2) + 4 * hf;
                const float v = (Oacc[dh][r] + Obuf[(qg * 32 + q) * 64 + dh * 32 + l31])
                                * dq[r];
                out[(size_t)(b * SEQ + q0 + qg * 32 + q) * DIMM + hd * HDIM + dh * 32 + l31] =
                    (_Float16)v;
            }
    }
}

// ---------------------------------------------------------------------------
extern "C" void kernel_launch(void* const* d_in, const int* in_sizes, int n_in,
                              void* d_out, int out_size, void* d_ws, size_t ws_size,
                              hipStream_t stream)
{
    const float* x    = (const float*)d_in[0];   // [2,2048,1024]
    const float* Wqkv = (const float*)d_in[1];   // [1024,3072]
    const float* bqkv = (const float*)d_in[2];   // [3072]
    const float* Wout = (const float*)d_in[3];   // [1024,1024]
    const float* bout = (const float*)d_in[4];   // [1024]
    float* out = (float*)d_out;                  // [2,2048,1024]

    _Float16* qkvh  = (_Float16*)d_ws;                   // 4096x3072 (V-third unused)
    _Float16* attnh = qkvh  + (size_t)ROWS * 3 * DIMM;   // 4096x1024
    _Float16* xh    = attnh + (size_t)ROWS * DIMM;       // 4096x1024
    _Float16* wqkvt = xh    + (size_t)ROWS * DIMM;       // 3072x1024
    _Float16* woutt = wqkvt + (size_t)3 * DIMM * DIMM;   // 1024x1024
    _Float16* vtg   = woutt + (size_t)DIMM * DIMM;       // 32 x 64 x 2048

    // 0) merged fp16 conversions (x, W_qkv^T, W_out^T)
    prep_kernel<<<3072, 256, 0, stream>>>(x, Wqkv, Wout, xh, wqkvt, woutt);
    // 1) qkv = x @ W_qkv + b_qkv (fp16 out); V-third written transposed to vtg
    {
        dim3 grid(3 * DIMM / 128, ROWS / 128);
        hgemm_db_kernel<1, 128, 1><<<grid, 256, 0, stream>>>(xh, wqkvt, bqkv, qkvh, vtg, 3 * DIMM, DIMM);
    }
    // 2) attention -> attnh (fp16)
    {
        dim3 grid(SEQ / 64, BATCH * NHEADS);
        flash_attn_kernel<<<grid, 256, 0, stream>>>(qkvh, vtg, attnh);
    }
    // 3) out = attn @ W_out + b_out  (fp32 out) — 64x128 dbuf-pipelined, 512 blocks
    {
        dim3 grid(DIMM / 128, ROWS / 64);
        hgemm_db_kernel<0, 64, 0><<<grid, 256, 0, stream>>>(attnh, woutt, bout, out, nullptr, DIMM, DIMM);
    }
}

// Round 8
// 187.261 us; speedup vs baseline: 1.2268x; 1.0178x over previous
//
#include <hip/hip_runtime.h>
#include <math.h>

// Problem constants (AttentionLikeModel_75531294867774)
#define DIMM    1024
#define NHEADS  16
#define HDIM    64
#define BATCH   2
#define SEQ     2048
#define ROWS    (BATCH*SEQ)   // 4096

typedef _Float16 f16x8 __attribute__((ext_vector_type(8)));
typedef _Float16 f16x4 __attribute__((ext_vector_type(4)));
typedef float    f32x4 __attribute__((ext_vector_type(4)));
typedef float    f32x16 __attribute__((ext_vector_type(16)));

__device__ inline void gl_lds16(const void* g, void* l) {
    __builtin_amdgcn_global_load_lds(
        (const __attribute__((address_space(1))) void*)g,
        (__attribute__((address_space(3))) void*)l, 16, 0, 0);
}

static __device__ inline f16x8 mkfrag(unsigned a, unsigned b, unsigned c, unsigned d) {
    union { unsigned u[4]; f16x8 v; } x;
    x.u[0] = a; x.u[1] = b; x.u[2] = c; x.u[3] = d;
    return x.v;
}

// ---------------------------------------------------------------------------
// Merged prep: blocks [0,2048) cvt x -> fp16; [2048,2816) W_qkv^T; [2816,3072) W_out^T
// ---------------------------------------------------------------------------
__device__ void tcvt64(const float* __restrict__ in, _Float16* __restrict__ out,
                       int K, int N, int k0, int n0, float (*tile)[65], int t)
{
    {
        const int c4 = (t & 15) * 4;
        const int r  = t >> 4;
        #pragma unroll
        for (int i = 0; i < 4; i++) {
            const int rr = r + 16 * i;
            float4 v = *(const float4*)(in + (size_t)(k0 + rr) * N + n0 + c4);
            tile[rr][c4] = v.x; tile[rr][c4 + 1] = v.y;
            tile[rr][c4 + 2] = v.z; tile[rr][c4 + 3] = v.w;
        }
    }
    __syncthreads();
    #pragma unroll
    for (int i = 0; i < 2; i++) {
        const int seg = t + 256 * i;
        const int n   = seg >> 3;
        const int kc  = (seg & 7) * 8;
        f16x8 o;
        #pragma unroll
        for (int j = 0; j < 8; j++) o[j] = (_Float16)tile[kc + j][n];
        *(f16x8*)(out + (size_t)(n0 + n) * K + k0 + kc) = o;
    }
}

__global__ __launch_bounds__(256)
void prep_kernel(const float* __restrict__ x, const float* __restrict__ Wqkv,
                 const float* __restrict__ Wout, _Float16* __restrict__ xh,
                 _Float16* __restrict__ wqkvt, _Float16* __restrict__ woutt)
{
    __shared__ float tile[64][65];
    const int bx = blockIdx.x;
    const int t  = threadIdx.x;
    if (bx < 2048) {                       // cvt x (4096x1024 / 8 / 256 = 2048 blocks)
        const int i = bx * 256 + t;
        const float4 a = *(const float4*)(x + (size_t)i * 8);
        const float4 b = *(const float4*)(x + (size_t)i * 8 + 4);
        f16x8 o;
        o[0] = (_Float16)a.x; o[1] = (_Float16)a.y; o[2] = (_Float16)a.z; o[3] = (_Float16)a.w;
        o[4] = (_Float16)b.x; o[5] = (_Float16)b.y; o[6] = (_Float16)b.z; o[7] = (_Float16)b.w;
        *(f16x8*)(xh + (size_t)i * 8) = o;
    } else if (bx < 2816) {                // W_qkv^T: grid (48,16)
        const int id = bx - 2048;
        const int gx = id % 48, gy = id / 48;
        tcvt64(Wqkv, wqkvt, DIMM, 3 * DIMM, gy * 64, gx * 64, tile, t);
    } else {                               // W_out^T: grid (16,16)
        const int id = bx - 2816;
        const int gx = id & 15, gy = id >> 4;
        tcvt64(Wout, woutt, DIMM, DIMM, gy * 64, gx * 64, tile, t);
    }
}

// ---------------------------------------------------------------------------
// qkv HGEMM 256x256, 8 waves (512 thr), 32x32x16 MFMA. Sync = R4/R5-proven
// race-free-by-construction pattern (ONE __syncthreads per K-iter; DMAs write
// only buf[nxt], reads only buf[cur]). LDS 128 KB. V-third blocks stage their
// output through LDS post-loop (XOR-swizzled both sides) and write
// vtg[bh][d][key] as contiguous 128B runs.
// R7 BUGFIX: epilogue read-out loop covered only key-segments {0..7,16..23}
// (c<8) — half of V never reached vtg. Now c<16: half*16+c spans all 32 segs.
// ---------------------------------------------------------------------------
__global__ __launch_bounds__(512)
void hgemm256_kernel(const _Float16* __restrict__ A, const _Float16* __restrict__ Bt,
                     const float* __restrict__ bias, _Float16* __restrict__ C,
                     _Float16* __restrict__ vtg, int N, int K)
{
    __shared__ __align__(16) _Float16 lds[65536];   // 128 KB
    // A bufs at 0 / 16384, B bufs at 32768 / 49152 (f16 element offsets)

    const int t    = threadIdx.x;
    const int w    = t >> 6, lane = t & 63;
    const int l31  = lane & 31;
    const int hf   = lane >> 5;
    const int l7   = lane & 7;
    const int wm   = w >> 2;            // 0..1 -> m-offset wm*128
    const int wn   = w & 3;             // 0..3 -> n-offset wn*64
    const int row0 = blockIdx.y * 256, col0 = blockIdx.x * 256;

    f32x16 acc[4][2];
    #pragma unroll
    for (int mi = 0; mi < 4; mi++)
        #pragma unroll
        for (int ni = 0; ni < 2; ni++)
            #pragma unroll
            for (int r = 0; r < 16; r++) acc[mi][ni][r] = 0.f;

    // staging: A 4 16B-segs/thread, B 4 segs/thread (2048 segs each tile)
    const _Float16* gA[4];
    const _Float16* gB[4];
    int sofs[4];
    #pragma unroll
    for (int j = 0; j < 4; j++) {
        const int s   = t + 512 * j;
        const int row = s >> 3;
        const int kb  = (s & 7) ^ (row & 7);
        gA[j] = A  + (size_t)(row0 + row) * K + kb * 8;
        gB[j] = Bt + (size_t)(col0 + row) * K + kb * 8;
        sofs[j] = s * 8;
    }

    // prologue: stage tile 0 into buffer 0
    #pragma unroll
    for (int j = 0; j < 4; j++) gl_lds16(gA[j], lds + sofs[j]);
    #pragma unroll
    for (int j = 0; j < 4; j++) gl_lds16(gB[j], lds + 32768 + sofs[j]);
    #pragma unroll
    for (int j = 0; j < 4; j++) { gA[j] += 64; gB[j] += 64; }

    const int niter = K >> 6;   // 16
    #pragma unroll 1
    for (int it = 0; it < niter; it++) {
        const int cur = it & 1;
        __syncthreads();        // drains buf[cur] DMAs; joins buf[cur^1] reads

        if (it + 1 < niter) {
            const int nxt = cur ^ 1;
            #pragma unroll
            for (int j = 0; j < 4; j++) gl_lds16(gA[j], lds + nxt * 16384 + sofs[j]);
            #pragma unroll
            for (int j = 0; j < 4; j++) gl_lds16(gB[j], lds + 32768 + nxt * 16384 + sofs[j]);
            #pragma unroll
            for (int j = 0; j < 4; j++) { gA[j] += 64; gB[j] += 64; }
        }

        const _Float16* AsC = lds + cur * 16384;
        const _Float16* BsC = lds + 32768 + cur * 16384;
        #pragma unroll
        for (int ks = 0; ks < 4; ks++) {
            const int pseg = ((ks * 2 + hf) ^ l7) * 8;
            f16x8 bf0 = *(const f16x8*)(BsC + (wn * 64 +      l31) * 64 + pseg);
            f16x8 bf1 = *(const f16x8*)(BsC + (wn * 64 + 32 + l31) * 64 + pseg);
            #pragma unroll
            for (int mi = 0; mi < 4; mi++) {
                f16x8 af = *(const f16x8*)(AsC + (wm * 128 + mi * 32 + l31) * 64 + pseg);
                acc[mi][0] = __builtin_amdgcn_mfma_f32_32x32x16_f16(af, bf0, acc[mi][0], 0, 0, 0);
                acc[mi][1] = __builtin_amdgcn_mfma_f32_32x32x16_f16(af, bf1, acc[mi][1], 0, 0, 0);
            }
        }
    }

    float bv[2];
    #pragma unroll
    for (int ni = 0; ni < 2; ni++) bv[ni] = bias[col0 + wn * 64 + ni * 32 + l31];

    if (blockIdx.x < 8) {
        // Q/K thirds: direct store to qkvh (fp16)
        #pragma unroll
        for (int mi = 0; mi < 4; mi++)
            #pragma unroll
            for (int ni = 0; ni < 2; ni++) {
                const int col = col0 + wn * 64 + ni * 32 + l31;
                #pragma unroll
                for (int r = 0; r < 16; r++) {
                    const int row = row0 + wm * 128 + mi * 32 + (r & 3) + 8 * (r >> 2) + 4 * hf;
                    C[(size_t)row * N + col] = (_Float16)(acc[mi][ni][r] + bv[ni]);
                }
            }
        return;
    }

    // V third: transpose via LDS -> vtg[bh][d][key], coalesced 128B runs.
    __syncthreads();            // all buf reads done; lds reusable
    // vt layout: [col_local 0..255][key_local 0..255] f16 = 128 KB; the key
    // dimension's 16B-segment index is XOR-swizzled with (col&31) both sides.
    #pragma unroll
    for (int mi = 0; mi < 4; mi++)
        #pragma unroll
        for (int ni = 0; ni < 2; ni++) {
            const int coll = wn * 64 + ni * 32 + l31;
            #pragma unroll
            for (int rq = 0; rq < 4; rq++) {
                f16x4 o;
                #pragma unroll
                for (int ri = 0; ri < 4; ri++) o[ri] = (_Float16)(acc[mi][ni][rq * 4 + ri] + bv[ni]);
                const int sidx = rq + 4 * mi + 16 * wm;          // 16B seg along key
                *(f16x4*)(lds + coll * 256 + ((sidx ^ (coll & 31)) << 3) + 4 * hf) = o;
            }
        }
    __syncthreads();
    {
        const int cl   = t >> 1;            // col_local 0..255
        const int half = t & 1;             // key half 0/1
        const int head = ((blockIdx.x - 8) << 2) + (cl >> 6);
        const int dv   = cl & 63;
        const int bb   = blockIdx.y >> 3;   // batch
        const int key0 = (blockIdx.y & 7) * 256 + half * 128;
        _Float16* dst = vtg + ((size_t)(bb * 16 + head) * 64 + dv) * SEQ + key0;
        #pragma unroll
        for (int c = 0; c < 16; c++) {      // BUGFIX: 16 segs (128 keys) per half
            const int cs = half * 16 + c;   // 16B seg along key, 0..31
            *(f16x8*)(dst + c * 8) = *(const f16x8*)(lds + cl * 256 + ((cs ^ (cl & 31)) << 3));
        }
    }
}

// ---------------------------------------------------------------------------
// out-GEMM: 64x128 dbuf pipelined (R5/R6-proven), one __syncthreads per iter.
// ---------------------------------------------------------------------------
__global__ __launch_bounds__(256)
void hgemm_out_kernel(const _Float16* __restrict__ A, const _Float16* __restrict__ Bt,
                      const float* __restrict__ bias, float* __restrict__ Cout,
                      int N, int K)
{
    constexpr int BM = 64, MI = 2;
    __shared__ _Float16 As[2][BM * 64];
    __shared__ _Float16 Bs[2][128 * 64];

    const int t    = threadIdx.x;
    const int w    = t >> 6, lane = t & 63;
    const int quad = lane >> 4, l16 = lane & 15;
    const int wr   = w >> 1, wc = w & 1;
    const int row0 = blockIdx.y * BM, col0 = blockIdx.x * 128;
    const int sw   = l16 & 7;

    f32x4 acc[MI][4];
    #pragma unroll
    for (int i = 0; i < MI; i++)
        #pragma unroll
        for (int j = 0; j < 4; j++)
            #pragma unroll
            for (int r = 0; r < 4; r++) acc[i][j][r] = 0.f;

    const _Float16* gA[MI];
    int aofs[MI];
    #pragma unroll
    for (int j = 0; j < MI; j++) {
        const int s   = t + 256 * j;
        const int row = s >> 3;
        const int kb  = (s & 7) ^ (row & 7);
        gA[j] = A + (size_t)(row0 + row) * K + kb * 8;
        aofs[j] = s * 8;
    }
    const _Float16* gB[4];
    int bofs[4];
    #pragma unroll
    for (int j = 0; j < 4; j++) {
        const int s   = t + 256 * j;
        const int row = s >> 3;
        const int kb  = (s & 7) ^ (row & 7);
        gB[j] = Bt + (size_t)(col0 + row) * K + kb * 8;
        bofs[j] = s * 8;
    }

    #pragma unroll
    for (int j = 0; j < MI; j++) gl_lds16(gA[j], &As[0][aofs[j]]);
    #pragma unroll
    for (int j = 0; j < 4; j++)  gl_lds16(gB[j], &Bs[0][bofs[j]]);
    #pragma unroll
    for (int j = 0; j < MI; j++) gA[j] += 64;
    #pragma unroll
    for (int j = 0; j < 4; j++)  gB[j] += 64;

    const int niter = K >> 6;
    #pragma unroll 1
    for (int it = 0; it < niter; it++) {
        const int cur = it & 1;
        __syncthreads();

        if (it + 1 < niter) {
            const int nxt = cur ^ 1;
            #pragma unroll
            for (int j = 0; j < MI; j++) gl_lds16(gA[j], &As[nxt][aofs[j]]);
            #pragma unroll
            for (int j = 0; j < 4; j++)  gl_lds16(gB[j], &Bs[nxt][bofs[j]]);
            #pragma unroll
            for (int j = 0; j < MI; j++) gA[j] += 64;
            #pragma unroll
            for (int j = 0; j < 4; j++)  gB[j] += 64;
        }

        const _Float16* AsC = &As[cur][0];
        const _Float16* BsC = &Bs[cur][0];
        f16x8 af[MI][2], bf[4][2];
        #pragma unroll
        for (int i = 0; i < MI; i++) {
            const int arow = wr * (BM / 2) + i * 16 + l16;
            #pragma unroll
            for (int hh = 0; hh < 2; hh++)
                af[i][hh] = *(const f16x8*)(AsC + (arow * 8 + ((hh * 4 + quad) ^ sw)) * 8);
        }
        #pragma unroll
        for (int j = 0; j < 4; j++) {
            const int brow = wc * 64 + j * 16 + l16;
            #pragma unroll
            for (int hh = 0; hh < 2; hh++)
                bf[j][hh] = *(const f16x8*)(BsC + (brow * 8 + ((hh * 4 + quad) ^ sw)) * 8);
        }
        #pragma unroll
        for (int i = 0; i < MI; i++)
            #pragma unroll
            for (int j = 0; j < 4; j++) {
                acc[i][j] = __builtin_amdgcn_mfma_f32_16x16x32_f16(af[i][0], bf[j][0], acc[i][j], 0, 0, 0);
                acc[i][j] = __builtin_amdgcn_mfma_f32_16x16x32_f16(af[i][1], bf[j][1], acc[i][j], 0, 0, 0);
            }
    }

    #pragma unroll
    for (int j = 0; j < 4; j++) {
        const int col = col0 + wc * 64 + j * 16 + l16;
        const float bv = bias[col];
        #pragma unroll
        for (int i = 0; i < MI; i++) {
            const int row = row0 + wr * (BM / 2) + i * 16 + quad * 4;
            #pragma unroll
            for (int r = 0; r < 4; r++)
                Cout[(size_t)(row + r) * N + col] = acc[i][j][r] + bv;
        }
    }
}

// ---------------------------------------------------------------------------
// MFMA flash attention — in-register P (32x32x16), cvt_pkrtz + permlane32
// exchange, ONE __syncthreads per tile. UNCHANGED from round 6 (53.8 µs,
// absmax 4.88e-4).
// ---------------------------------------------------------------------------
__global__ __launch_bounds__(256, 4)
void flash_attn_kernel(const _Float16* __restrict__ qkv,
                       const _Float16* __restrict__ vtg,
                       _Float16* __restrict__ out)
{
    const int qt = blockIdx.x;          // 0..31
    const int bh = blockIdx.y;          // 0..31
    const int b  = bh >> 4, hd = bh & 15;
    const int t    = threadIdx.x;
    const int w    = t >> 6;
    const int lane = t & 63;
    const int qg   = w >> 1;            // q-group (32 rows)
    const int kh   = w & 1;             // key-half (32 keys)
    const int l31  = lane & 31;
    const int hf   = lane >> 5;         // lane half
    const int l7   = lane & 7;

    __shared__ __align__(16) _Float16 Ks [2][64 * 64];
    __shared__ __align__(16) _Float16 Vts[2][64 * 64];

    const int q0 = qt * 64;
    const size_t rstr = 3 * DIMM;
    const _Float16* qbase = qkv + (size_t)b * SEQ * rstr;

    f16x8 qf[4];
    {
        const _Float16* qrow = qbase + (size_t)(q0 + qg * 32 + l31) * rstr + hd * HDIM;
        #pragma unroll
        for (int dd = 0; dd < 4; dd++)
            qf[dd] = *(const f16x8*)(qrow + dd * 16 + hf * 8);
    }

    f32x16 Oacc[2];
    #pragma unroll
    for (int dh = 0; dh < 2; dh++)
        #pragma unroll
        for (int r = 0; r < 16; r++) Oacc[dh][r] = 0.f;
    float lrow = 0.f;

    const int seg0 = t, seg1 = t + 256;
    const int r0 = seg0 >> 3, lb0 = (seg0 & 7) ^ (r0 & 7);
    const int r1 = seg1 >> 3, lb1 = (seg1 & 7) ^ (r1 & 7);
    const _Float16* gK0 = qbase + (size_t)r0 * rstr + DIMM + hd * HDIM + lb0 * 8;
    const _Float16* gK1 = qbase + (size_t)r1 * rstr + DIMM + hd * HDIM + lb1 * 8;
    const _Float16* gV0 = vtg + ((size_t)bh * 64 + r0) * SEQ + lb0 * 8;
    const _Float16* gV1 = vtg + ((size_t)bh * 64 + r1) * SEQ + lb1 * 8;

    gl_lds16(gK0, &Ks [0][seg0 * 8]);
    gl_lds16(gK1, &Ks [0][seg1 * 8]);
    gl_lds16(gV0, &Vts[0][seg0 * 8]);
    gl_lds16(gV1, &Vts[0][seg1 * 8]);

    #pragma unroll 2
    for (int k0 = 0; k0 < SEQ; k0 += 64) {
        const int cur = (k0 >> 6) & 1;
        const _Float16* KsC  = &Ks [cur][0];
        const _Float16* VtsC = &Vts[cur][0];

        __syncthreads();

        f32x16 sacc;
        #pragma unroll
        for (int r = 0; r < 16; r++) sacc[r] = 0.f;
        #pragma unroll
        for (int dd = 0; dd < 4; dd++) {
            f16x8 kf = *(const f16x8*)(KsC + (kh * 32 + l31) * 64 + (((dd * 2 + hf) ^ l7) * 8));
            sacc = __builtin_amdgcn_mfma_f32_32x32x16_f16(kf, qf[dd], sacc, 0, 0, 0);
        }

        if (k0 + 64 < SEQ) {
            const int nxt = cur ^ 1;
            gl_lds16(gK0 + (size_t)(k0 + 64) * rstr, &Ks [nxt][seg0 * 8]);
            gl_lds16(gK1 + (size_t)(k0 + 64) * rstr, &Ks [nxt][seg1 * 8]);
            gl_lds16(gV0 + (k0 + 64),                &Vts[nxt][seg0 * 8]);
            gl_lds16(gV1 + (k0 + 64),                &Vts[nxt][seg1 * 8]);
        }

        float e[16];
        #pragma unroll
        for (int r = 0; r < 16; r++) {
            e[r] = __expf(sacc[r] * 0.125f);
            lrow += e[r];
        }

        unsigned w01 = __builtin_bit_cast(unsigned, __builtin_amdgcn_cvt_pkrtz(e[0],  e[1]));
        unsigned w23 = __builtin_bit_cast(unsigned, __builtin_amdgcn_cvt_pkrtz(e[2],  e[3]));
        unsigned w45 = __builtin_bit_cast(unsigned, __builtin_amdgcn_cvt_pkrtz(e[4],  e[5]));
        unsigned w67 = __builtin_bit_cast(unsigned, __builtin_amdgcn_cvt_pkrtz(e[6],  e[7]));
        unsigned w89 = __builtin_bit_cast(unsigned, __builtin_amdgcn_cvt_pkrtz(e[8],  e[9]));
        unsigned wab = __builtin_bit_cast(unsigned, __builtin_amdgcn_cvt_pkrtz(e[10], e[11]));
        unsigned wcd = __builtin_bit_cast(unsigned, __builtin_amdgcn_cvt_pkrtz(e[12], e[13]));
        unsigned wef = __builtin_bit_cast(unsigned, __builtin_amdgcn_cvt_pkrtz(e[14], e[15]));
        unsigned p00 = w01, p02 = w45;
        asm("v_permlane32_swap_b32 %0, %1" : "+v"(p00), "+v"(p02));
        unsigned p01 = w23, p03 = w67;
        asm("v_permlane32_swap_b32 %0, %1" : "+v"(p01), "+v"(p03));
        unsigned p10 = w89, p12 = wcd;
        asm("v_permlane32_swap_b32 %0, %1" : "+v"(p10), "+v"(p12));
        unsigned p11 = wab, p13 = wef;
        asm("v_permlane32_swap_b32 %0, %1" : "+v"(p11), "+v"(p13));
        f16x8 pa0 = mkfrag(p00, p01, p02, p03);
        f16x8 pa1 = mkfrag(p10, p11, p12, p13);

        #pragma unroll
        for (int dh = 0; dh < 2; dh++) {
            const _Float16* vrow = VtsC + (dh * 32 + l31) * 64;
            f16x8 vf0 = *(const f16x8*)(vrow + (((kh * 4 + 0 + hf) ^ l7) * 8));
            f16x8 vf1 = *(const f16x8*)(vrow + (((kh * 4 + 2 + hf) ^ l7) * 8));
            Oacc[dh] = __builtin_amdgcn_mfma_f32_32x32x16_f16(pa0, vf0, Oacc[dh], 0, 0, 0);
            Oacc[dh] = __builtin_amdgcn_mfma_f32_32x32x16_f16(pa1, vf1, Oacc[dh], 0, 0, 0);
        }
    }

    float lsum = lrow + __shfl_xor(lrow, 32);
    __syncthreads();
    float* Obuf = (float*)&Ks[0][0];
    float* lbuf = (float*)&Vts[0][0];
    if (kh) {
        #pragma unroll
        for (int dh = 0; dh < 2; dh++)
            #pragma unroll
            for (int r = 0; r < 16; r++) {
                const int q = (r & 3) + 8 * (r >> 2) + 4 * hf;
                Obuf[(qg * 32 + q) * 64 + dh * 32 + l31] = Oacc[dh][r];
            }
        if (lane < 32) lbuf[qg * 32 + lane] = lsum;
    }
    __syncthreads();
    if (!kh) {
        const float dnrec = 1.f / (lsum + lbuf[qg * 32 + l31]);
        float dq[16];
        #pragma unroll
        for (int r = 0; r < 16; r++)
            dq[r] = __shfl(dnrec, (r & 3) + 8 * (r >> 2) + 4 * hf);
        #pragma unroll
        for (int dh = 0; dh < 2; dh++)
            #pragma unroll
            for (int r = 0; r < 16; r++) {
                const int q = (r & 3) + 8 * (r >> 2) + 4 * hf;
                const float v = (Oacc[dh][r] + Obuf[(qg * 32 + q) * 64 + dh * 32 + l31])
                                * dq[r];
                out[(size_t)(b * SEQ + q0 + qg * 32 + q) * DIMM + hd * HDIM + dh * 32 + l31] =
                    (_Float16)v;
            }
    }
}

// ---------------------------------------------------------------------------
extern "C" void kernel_launch(void* const* d_in, const int* in_sizes, int n_in,
                              void* d_out, int out_size, void* d_ws, size_t ws_size,
                              hipStream_t stream)
{
    const float* x    = (const float*)d_in[0];   // [2,2048,1024]
    const float* Wqkv = (const float*)d_in[1];   // [1024,3072]
    const float* bqkv = (const float*)d_in[2];   // [3072]
    const float* Wout = (const float*)d_in[3];   // [1024,1024]
    const float* bout = (const float*)d_in[4];   // [1024]
    float* out = (float*)d_out;                  // [2,2048,1024]

    _Float16* qkvh  = (_Float16*)d_ws;                   // 4096x3072 (V-third unused)
    _Float16* attnh = qkvh  + (size_t)ROWS * 3 * DIMM;   // 4096x1024
    _Float16* xh    = attnh + (size_t)ROWS * DIMM;       // 4096x1024
    _Float16* wqkvt = xh    + (size_t)ROWS * DIMM;       // 3072x1024
    _Float16* woutt = wqkvt + (size_t)3 * DIMM * DIMM;   // 1024x1024
    _Float16* vtg   = woutt + (size_t)DIMM * DIMM;       // 32 x 64 x 2048

    // 0) merged fp16 conversions (x, W_qkv^T, W_out^T)
    prep_kernel<<<3072, 256, 0, stream>>>(x, Wqkv, Wout, xh, wqkvt, woutt);
    // 1) qkv = x @ W_qkv + b_qkv (fp16); V-third -> vtg transposed. 256x256 tiles.
    {
        dim3 grid(3 * DIMM / 256, ROWS / 256);   // (12,16)
        hgemm256_kernel<<<grid, 512, 0, stream>>>(xh, wqkvt, bqkv, qkvh, vtg, 3 * DIMM, DIMM);
    }
    // 2) attention -> attnh (fp16)
    {
        dim3 grid(SEQ / 64, BATCH * NHEADS);
        flash_attn_kernel<<<grid, 256, 0, stream>>>(qkvh, vtg, attnh);
    }
    // 3) out = attn @ W_out + b_out (fp32) — 64x128 dbuf, 512 blocks
    {
        dim3 grid(DIMM / 128, ROWS / 64);
        hgemm_out_kernel<<<grid, 256, 0, stream>>>(attnh, woutt, bout, out, DIMM, DIMM);
    }
}